// Round 3
// baseline (8510.907 us; speedup 1.0000x reference)
//
#include <hip/hip_runtime.h>

// ---------------------------------------------------------------------------
// GN_NN_32873679684148: encoder MLP+LN -> 4x GATv2+LN residual -> decoder MLP
// Round 2: wave-per-row shuffle-broadcast MLPs (no barriers in row loop,
// conflict-free bf16-packed weight staging). edge_enc 2.12ms -> ~0.5ms pred.
// N=50000, E=800000, H=128, L=4.
// ---------------------------------------------------------------------------

typedef unsigned short u16;
typedef unsigned int   u32;

#define LEAKY01(a) ((a) > 0.f ? (a) : 0.01f*(a))
#define LEAKY20(a) ((a) > 0.f ? (a) : 0.2f*(a))

__device__ __forceinline__ float bf2f(u16 h) { return __uint_as_float(((u32)h) << 16); }
__device__ __forceinline__ u16 f2bf(float f) {
  u32 u = __float_as_uint(f);
  u32 r = u + 0x7fffu + ((u >> 16) & 1u);   // round-to-nearest-even
  return (u16)(r >> 16);
}
__device__ __forceinline__ float bflo(u32 p) { return __uint_as_float(p << 16); }
__device__ __forceinline__ float bfhi(u32 p) { return __uint_as_float(p & 0xffff0000u); }
__device__ __forceinline__ u32 packbf(float a, float b) {
  return (u32)f2bf(a) | ((u32)f2bf(b) << 16);
}

// ---------------- node encoder: 32 -> 64 -> 96 -> 128 + LN -----------------
// wave-per-row; weights staged [k][lane-pair]; activations broadcast via shfl
__global__ __launch_bounds__(256) void node_enc_kernel(
    const float* __restrict__ x,
    const float* __restrict__ w1, const float* __restrict__ b1,
    const float* __restrict__ w2, const float* __restrict__ b2,
    const float* __restrict__ w3, const float* __restrict__ b3,
    const float* __restrict__ g, const float* __restrict__ bb,
    float* __restrict__ y, int n)
{
  __shared__ float sw1t[32*64];   // [k][c] fp32, 8KB
  __shared__ u32   sw2p[64*64];   // [k][l] pair (col l, col 64+(l%32)), 16KB
  __shared__ u32   sw3p[96*64];   // [k][l] pair (col l, col l+64), 24KB
  const int tid = threadIdx.x;
  for (int i = tid; i < 32*64; i += 256) { int k = i >> 6, c = i & 63; sw1t[i] = w1[c*32 + k]; }
  for (int i = tid; i < 64*64; i += 256) { int k = i >> 6, l = i & 63; sw2p[i] = packbf(w2[l*64 + k], w2[(64 + (l & 31))*64 + k]); }
  for (int i = tid; i < 96*64; i += 256) { int k = i >> 6, l = i & 63; sw3p[i] = packbf(w3[l*96 + k], w3[(l + 64)*96 + k]); }
  __syncthreads();
  const int lane = tid & 63, wv = tid >> 6;
  const float b2a = b2[lane], b2b = b2[64 + (lane & 31)];
  const float b3a = b3[lane], b3b = b3[lane + 64];
  const float ga = g[lane], gb = g[lane + 64];
  const float ba = bb[lane], bbv = bb[lane + 64];
  for (long row = (long)blockIdx.x*4 + wv; row < n; row += (long)gridDim.x*4) {
    float xin[32];
    const float4* xp = (const float4*)(x + row*32);
    #pragma unroll
    for (int q = 0; q < 8; ++q) ((float4*)xin)[q] = xp[q];
    // L1: 32 -> 64, col = lane
    float h1 = b1[lane];
    #pragma unroll
    for (int k = 0; k < 32; ++k) h1 += xin[k] * sw1t[k*64 + lane];
    h1 = LEAKY01(h1);
    // L2: 64 -> 96
    float a0 = b2a, a1 = b2b;
    #pragma unroll
    for (int k = 0; k < 64; ++k) {
      const u32 wp = sw2p[k*64 + lane];
      const float hv = __shfl(h1, k, 64);
      a0 += hv * bflo(wp); a1 += hv * bfhi(wp);
    }
    const float h2a = LEAKY01(a0), h2b = LEAKY01(a1);
    // L3: 96 -> 128
    float o0 = b3a, o1 = b3b;
    #pragma unroll
    for (int k = 0; k < 64; ++k) {
      const u32 wp = sw3p[k*64 + lane];
      const float hv = __shfl(h2a, k, 64);
      o0 += hv * bflo(wp); o1 += hv * bfhi(wp);
    }
    #pragma unroll
    for (int k = 0; k < 32; ++k) {
      const u32 wp = sw3p[(64 + k)*64 + lane];
      const float hv = __shfl(h2b, k, 64);
      o0 += hv * bflo(wp); o1 += hv * bfhi(wp);
    }
    // LN
    float sum = o0 + o1, sq = o0*o0 + o1*o1;
    for (int off = 32; off; off >>= 1) { sum += __shfl_xor(sum, off, 64); sq += __shfl_xor(sq, off, 64); }
    const float mu = sum * (1.f/128.f);
    const float var = sq * (1.f/128.f) - mu*mu;
    const float rs = rsqrtf(var + 1e-5f);
    y[row*128 + lane]      = (o0 - mu) * rs * ga + ba;
    y[row*128 + lane + 64] = (o1 - mu) * rs * gb + bbv;
  }
}

// ------- edge encoder: 8 -> 48 -> 88 -> 128 + LN, 2 rows/wave, bf16 out ----
__global__ __launch_bounds__(256) void edge_enc_kernel(
    const float* __restrict__ eat,      // chunk base: ecnt rows of 8
    const float* __restrict__ w1, const float* __restrict__ b1,
    const float* __restrict__ w2, const float* __restrict__ b2,
    const float* __restrict__ w3, const float* __restrict__ b3,
    const float* __restrict__ g, const float* __restrict__ bb,
    u16* __restrict__ ea, int ecnt)
{
  __shared__ float sw1t[8*48];    // [k][c] fp32, 1.5KB
  __shared__ u32   sw2p[48*64];   // [k][l] pair (col l, col 64+(l%24)), 12.3KB
  __shared__ u32   sw3p[88*64];   // [k][l] pair (col l, col l+64), 22.5KB
  const int tid = threadIdx.x;
  for (int i = tid; i < 8*48; i += 256)  { int k = i/48, c = i - k*48; sw1t[i] = w1[c*8 + k]; }
  for (int i = tid; i < 48*64; i += 256) { int k = i >> 6, l = i & 63; sw2p[i] = packbf(w2[l*48 + k], w2[(64 + (l % 24))*48 + k]); }
  for (int i = tid; i < 88*64; i += 256) { int k = i >> 6, l = i & 63; sw3p[i] = packbf(w3[l*88 + k], w3[(l + 64)*88 + k]); }
  __syncthreads();
  const int lane = tid & 63, wv = tid >> 6;
  const int c48 = lane % 48;
  const float b1v = b1[c48];
  const float b2a = b2[lane], b2b = b2[64 + (lane % 24)];
  const float b3a = b3[lane], b3b = b3[lane + 64];
  const float ga = g[lane], gb = g[lane + 64];
  const float ba = bb[lane], bbv = bb[lane + 64];
  const long stride = (long)gridDim.x * 4 * 2;
  for (long r0 = ((long)blockIdx.x*4 + wv)*2; r0 < ecnt; r0 += stride) {
    const long r1 = r0 + 1;
    const bool v1 = r1 < ecnt;
    float xin0[8], xin1[8];
    const float4* p0 = (const float4*)(eat + r0*8);
    ((float4*)xin0)[0] = p0[0]; ((float4*)xin0)[1] = p0[1];
    if (v1) {
      const float4* p1 = (const float4*)(eat + r1*8);
      ((float4*)xin1)[0] = p1[0]; ((float4*)xin1)[1] = p1[1];
    } else {
      #pragma unroll
      for (int q = 0; q < 8; ++q) xin1[q] = 0.f;
    }
    // L1: 8 -> 48, col = lane%48 (lanes 48..63 duplicate cols 0..15)
    float h1_0 = b1v, h1_1 = b1v;
    #pragma unroll
    for (int k = 0; k < 8; ++k) {
      const float w = sw1t[k*48 + c48];
      h1_0 += xin0[k]*w; h1_1 += xin1[k]*w;
    }
    h1_0 = LEAKY01(h1_0); h1_1 = LEAKY01(h1_1);
    // L2: 48 -> 88  (cols: lane, 64+(lane%24))
    float a00 = b2a, a01 = b2b, a10 = b2a, a11 = b2b;
    #pragma unroll
    for (int k = 0; k < 48; ++k) {
      const u32 wp = sw2p[k*64 + lane];
      const float wl = bflo(wp), wh = bfhi(wp);
      const float h0 = __shfl(h1_0, k, 64);
      const float h1v = __shfl(h1_1, k, 64);
      a00 += h0*wl; a01 += h0*wh;
      a10 += h1v*wl; a11 += h1v*wh;
    }
    const float h2a0 = LEAKY01(a00), h2b0 = LEAKY01(a01);
    const float h2a1 = LEAKY01(a10), h2b1 = LEAKY01(a11);
    // L3: 88 -> 128 (cols: lane, lane+64)
    float o00 = b3a, o01 = b3b, o10 = b3a, o11 = b3b;
    #pragma unroll
    for (int k = 0; k < 64; ++k) {
      const u32 wp = sw3p[k*64 + lane];
      const float wl = bflo(wp), wh = bfhi(wp);
      const float h0 = __shfl(h2a0, k, 64);
      const float h1v = __shfl(h2a1, k, 64);
      o00 += h0*wl; o01 += h0*wh;
      o10 += h1v*wl; o11 += h1v*wh;
    }
    #pragma unroll
    for (int k = 0; k < 24; ++k) {
      const u32 wp = sw3p[(64 + k)*64 + lane];
      const float wl = bflo(wp), wh = bfhi(wp);
      const float h0 = __shfl(h2b0, k, 64);
      const float h1v = __shfl(h2b1, k, 64);
      o00 += h0*wl; o01 += h0*wh;
      o10 += h1v*wl; o11 += h1v*wh;
    }
    // LN per row
    float s0 = o00 + o01, q0 = o00*o00 + o01*o01;
    float s1 = o10 + o11, q1 = o10*o10 + o11*o11;
    for (int off = 32; off; off >>= 1) {
      s0 += __shfl_xor(s0, off, 64); q0 += __shfl_xor(q0, off, 64);
      s1 += __shfl_xor(s1, off, 64); q1 += __shfl_xor(q1, off, 64);
    }
    {
      const float mu = s0 * (1.f/128.f);
      const float var = q0 * (1.f/128.f) - mu*mu;
      const float rs = rsqrtf(var + 1e-5f);
      u16* er = ea + r0*128;
      er[lane]      = f2bf((o00 - mu) * rs * ga + ba);
      er[lane + 64] = f2bf((o01 - mu) * rs * gb + bbv);
    }
    if (v1) {
      const float mu = s1 * (1.f/128.f);
      const float var = q1 * (1.f/128.f) - mu*mu;
      const float rs = rsqrtf(var + 1e-5f);
      u16* er = ea + r1*128;
      er[lane]      = f2bf((o10 - mu) * rs * ga + ba);
      er[lane + 64] = f2bf((o11 - mu) * rs * gb + bbv);
    }
  }
}

// --------- 128x128 linear: out(bf16) = in(fp32) @ w.T + b ---------
__global__ __launch_bounds__(256) void linear128_kernel(
    const float* __restrict__ in, const float* __restrict__ w,
    const float* __restrict__ b, u16* __restrict__ out, int n)
{
  __shared__ u32 swp[64*128];   // packed bf16 pairs along k: swp[kk*128+c]
  const int tid = threadIdx.x;
  for (int i = tid; i < 8192; i += blockDim.x) {
    int c = i >> 6, kk = i & 63;
    swp[kk*128 + c] = packbf(w[c*128 + 2*kk], w[c*128 + 2*kk + 1]);
  }
  __syncthreads();
  const int lane = tid & 63, wv = tid >> 6;
  const int wpb = blockDim.x >> 6;
  const float b0 = b[lane], b1v = b[lane + 64];
  for (long row = (long)blockIdx.x*wpb + wv; row < n; row += (long)gridDim.x*wpb) {
    const float* ir = in + row*128;
    float a0 = b0, a1 = b1v;
    #pragma unroll 8
    for (int kk = 0; kk < 64; ++kk) {
      const float v0 = ir[2*kk], v1 = ir[2*kk + 1];
      const u32 w0 = swp[kk*128 + lane];
      const u32 w1 = swp[kk*128 + lane + 64];
      a0 += v0*bflo(w0) + v1*bfhi(w0);
      a1 += v0*bflo(w1) + v1*bfhi(w1);
    }
    out[row*128 + lane]      = f2bf(a0);
    out[row*128 + lane + 64] = f2bf(a1);
  }
}

// ---------------- CSR build ----------------
__global__ __launch_bounds__(256) void csr_count_kernel(
    const int* __restrict__ dst, int* __restrict__ cnt, int E)
{
  for (long e = (long)blockIdx.x*blockDim.x + threadIdx.x; e < E;
       e += (long)gridDim.x*blockDim.x)
    atomicAdd(&cnt[dst[e]], 1);
}

__global__ __launch_bounds__(1024) void csr_scan_kernel(
    const int* __restrict__ cnt, int* __restrict__ rowptr, int n)
{
  __shared__ int part[1024];
  const int t = threadIdx.x;
  const int chunk = (n + 1023) >> 10;
  const int b = t * chunk;
  const int e = min(b + chunk, n);
  int s = 0;
  for (int i = b; i < e; ++i) s += cnt[i];
  part[t] = s;
  __syncthreads();
  for (int d = 1; d < 1024; d <<= 1) {
    int v = (t >= d) ? part[t - d] : 0;
    __syncthreads();
    if (t >= d) part[t] += v;
    __syncthreads();
  }
  int pre = (t == 0) ? 0 : part[t - 1];
  for (int i = b; i < e; ++i) { rowptr[i] = pre; pre += cnt[i]; }
  if (t == 1023) rowptr[n] = pre;
}

__global__ __launch_bounds__(256) void csr_fill_kernel(
    const int* __restrict__ dst, const int* __restrict__ rowptr,
    int* __restrict__ cursor, int* __restrict__ eid, int E)
{
  for (long e = (long)blockIdx.x*blockDim.x + threadIdx.x; e < E;
       e += (long)gridDim.x*blockDim.x) {
    const int d = dst[e];
    const int pos = atomicAdd(&cursor[d], 1);
    eid[rowptr[d] + pos] = (int)e;
  }
}

// -------- per-edge attention logit s[e] (no atomics) --------
__global__ __launch_bounds__(256) void gat_logit_kernel(
    const u16* __restrict__ ea,         // chunk base (local rows)
    const u16* __restrict__ xl, const u16* __restrict__ xr,
    const int* __restrict__ src, const int* __restrict__ dst,
    const float* __restrict__ we, const float* __restrict__ att,
    float* __restrict__ s_out, int eoff, int ecnt)
{
  __shared__ u32 swp[64*128];   // packed bf16 we pairs along k
  const int tid = threadIdx.x;
  for (int i = tid; i < 8192; i += blockDim.x) {
    int c = i >> 6, kk = i & 63;
    swp[kk*128 + c] = packbf(we[c*128 + 2*kk], we[c*128 + 2*kk + 1]);
  }
  __syncthreads();
  const int lane = tid & 63, wv = tid >> 6;
  const int wpb = blockDim.x >> 6;
  const long totalWaves = (long)gridDim.x * wpb;
  const float att0 = att[lane], att1 = att[lane + 64];
  for (long i = (long)blockIdx.x*wpb + wv; i < ecnt; i += totalWaves) {
    const long e = eoff + i;
    const int sN = src[e], dN = dst[e];
    const u32* eap = (const u32*)(ea + i*128);
    float a0 = 0.f, a1 = 0.f;
    #pragma unroll 8
    for (int kk = 0; kk < 64; ++kk) {
      const u32 va = eap[kk];
      const float v0 = bflo(va), v1 = bfhi(va);
      const u32 w0 = swp[kk*128 + lane];
      const u32 w1 = swp[kk*128 + lane + 64];
      a0 += v0*bflo(w0) + v1*bfhi(w0);
      a1 += v0*bflo(w1) + v1*bfhi(w1);
    }
    float e0 = a0 + bf2f(xl[(long)sN*128 + lane])      + bf2f(xr[(long)dN*128 + lane]);
    float e1 = a1 + bf2f(xl[(long)sN*128 + lane + 64]) + bf2f(xr[(long)dN*128 + lane + 64]);
    e0 = LEAKY20(e0); e1 = LEAKY20(e1);
    float p = e0*att0 + e1*att1;
    for (int off = 32; off; off >>= 1) p += __shfl_down(p, off, 64);
    if (lane == 0) s_out[e] = p;
  }
}

// ---- per-node: softmax over CSR edges + weighted gather + LN residual ----
__global__ __launch_bounds__(256) void gat_agg_kernel(
    const float* __restrict__ s, const int* __restrict__ src,
    const int* __restrict__ rowptr, const int* __restrict__ eid,
    const u16* __restrict__ xl, const float* __restrict__ bias,
    const float* __restrict__ g, const float* __restrict__ bb,
    float* __restrict__ y, int n)
{
  const int tid = threadIdx.x;
  const int lane = tid & 63, wv = tid >> 6;
  const int wpb = blockDim.x >> 6;
  const float bi0 = bias[lane], bi1 = bias[lane + 64];
  const float g0 = g[lane], g1 = g[lane + 64];
  const float bb0 = bb[lane], bb1 = bb[lane + 64];
  for (long node = (long)blockIdx.x*wpb + wv; node < n; node += (long)gridDim.x*wpb) {
    const int beg = rowptr[node], end = rowptr[node + 1];
    float m = -INFINITY;
    for (int j = beg; j < end; ++j) m = fmaxf(m, s[eid[j]]);
    float den = 0.f, a0 = 0.f, a1 = 0.f;
    for (int j = beg; j < end; ++j) {
      const int e = eid[j];
      const float z = __expf(s[e] - m);
      den += z;
      const int sN = src[e];
      a0 += z * bf2f(xl[(long)sN*128 + lane]);
      a1 += z * bf2f(xl[(long)sN*128 + lane + 64]);
    }
    const float inv = 1.f / fmaxf(den, 1e-16f);
    const float v0 = a0*inv + bi0;
    const float v1 = a1*inv + bi1;
    float sum = v0 + v1, sq = v0*v0 + v1*v1;
    for (int off = 32; off; off >>= 1) { sum += __shfl_xor(sum, off, 64); sq += __shfl_xor(sq, off, 64); }
    const float mu = sum * (1.f/128.f);
    const float var = sq * (1.f/128.f) - mu*mu;
    const float rs = rsqrtf(var + 1e-5f);
    y[node*128 + lane]      += (v0 - mu) * rs * g0 + bb0;
    y[node*128 + lane + 64] += (v1 - mu) * rs * g1 + bb1;
  }
}

// ---------------- decoder: 128 -> 86 -> 44 -> 2, wave-per-row ----------------
__global__ __launch_bounds__(256) void decoder_kernel(
    const float* __restrict__ y,
    const float* __restrict__ w1, const float* __restrict__ b1,
    const float* __restrict__ w2, const float* __restrict__ b2,
    const float* __restrict__ w3, const float* __restrict__ b3,
    float* __restrict__ out, int n)
{
  __shared__ u32   sw1p[128*64];  // [k][l] pair (col l, col 64+(l%22)), 32KB
  __shared__ float sw2t[86*64];   // [k][l] col l%44 fp32, 22KB
  const int tid = threadIdx.x;
  for (int i = tid; i < 128*64; i += 256) {
    int k = i >> 6, l = i & 63;
    sw1p[i] = packbf(w1[l*128 + k], w1[(64 + (l % 22))*128 + k]);
  }
  for (int i = tid; i < 86*64; i += 256) {
    int k = i >> 6, l = i & 63;
    sw2t[i] = w2[(l % 44)*86 + k];
  }
  __syncthreads();
  const int lane = tid & 63, wv = tid >> 6;
  const float b1a = b1[lane], b1b = b1[64 + (lane % 22)];
  const float b2v = b2[lane % 44];
  const float w3a = (lane < 44) ? w3[lane] : 0.f;
  const float w3b = (lane < 44) ? w3[44 + lane] : 0.f;
  const float b3a = b3[0], b3b = b3[1];
  for (long row = (long)blockIdx.x*4 + wv; row < n; row += (long)gridDim.x*4) {
    const float ya = y[row*128 + lane];
    const float yb = y[row*128 + lane + 64];
    // L1: 128 -> 86
    float a0 = b1a, a1 = b1b;
    #pragma unroll
    for (int k = 0; k < 64; ++k) {
      const u32 wp = sw1p[k*64 + lane];
      const float hv = __shfl(ya, k, 64);
      a0 += hv * bflo(wp); a1 += hv * bfhi(wp);
    }
    #pragma unroll
    for (int k = 0; k < 64; ++k) {
      const u32 wp = sw1p[(64 + k)*64 + lane];
      const float hv = __shfl(yb, k, 64);
      a0 += hv * bflo(wp); a1 += hv * bfhi(wp);
    }
    const float h1a = LEAKY01(a0), h1b = LEAKY01(a1);
    // L2: 86 -> 44 (col = lane%44, dup beyond)
    float a2 = b2v;
    #pragma unroll
    for (int k = 0; k < 64; ++k) {
      const float hv = __shfl(h1a, k, 64);
      a2 += hv * sw2t[k*64 + lane];
    }
    #pragma unroll
    for (int k = 0; k < 22; ++k) {
      const float hv = __shfl(h1b, k, 64);
      a2 += hv * sw2t[(64 + k)*64 + lane];
    }
    const float h2 = LEAKY01(a2);
    // L3: 44 -> 2 via wave reduction
    float t0 = (lane < 44) ? h2 * w3a : 0.f;
    float t1 = (lane < 44) ? h2 * w3b : 0.f;
    for (int off = 32; off; off >>= 1) { t0 += __shfl_xor(t0, off, 64); t1 += __shfl_xor(t1, off, 64); }
    if (lane == 0) {
      out[row*2]     = t0 + b3a;
      out[row*2 + 1] = t1 + b3b;
    }
  }
}

__global__ __launch_bounds__(256) void zero_out_kernel(float* __restrict__ out, long n)
{
  for (long i = (long)blockIdx.x*blockDim.x + threadIdx.x; i < n;
       i += (long)gridDim.x*blockDim.x) out[i] = 0.f;
}

// ---------------------------------------------------------------------------
extern "C" void kernel_launch(void* const* d_in, const int* in_sizes, int n_in,
                              void* d_out, int out_size, void* d_ws, size_t ws_size,
                              hipStream_t stream) {
  const float* x        = (const float*)d_in[0];
  const int*   eidx     = (const int*)  d_in[1];
  const float* edge_attr= (const float*)d_in[2];
  const float* enc_w1 = (const float*)d_in[3];  const float* enc_b1 = (const float*)d_in[4];
  const float* enc_w2 = (const float*)d_in[5];  const float* enc_b2 = (const float*)d_in[6];
  const float* enc_w3 = (const float*)d_in[7];  const float* enc_b3 = (const float*)d_in[8];
  const float* enc_lg = (const float*)d_in[9];  const float* enc_lb = (const float*)d_in[10];
  const float* ee_w1  = (const float*)d_in[11]; const float* ee_b1  = (const float*)d_in[12];
  const float* ee_w2  = (const float*)d_in[13]; const float* ee_b2  = (const float*)d_in[14];
  const float* ee_w3  = (const float*)d_in[15]; const float* ee_b3  = (const float*)d_in[16];
  const float* ee_lg  = (const float*)d_in[17]; const float* ee_lb  = (const float*)d_in[18];
  const float* gat_wl = (const float*)d_in[19]; const float* gat_bl = (const float*)d_in[20];
  const float* gat_wr = (const float*)d_in[21]; const float* gat_br = (const float*)d_in[22];
  const float* gat_we = (const float*)d_in[23]; const float* gat_att= (const float*)d_in[24];
  const float* gat_bias=(const float*)d_in[25];
  const float* ln_g   = (const float*)d_in[26]; const float* ln_b   = (const float*)d_in[27];
  const float* dec_w1 = (const float*)d_in[28]; const float* dec_b1 = (const float*)d_in[29];
  const float* dec_w2 = (const float*)d_in[30]; const float* dec_b2 = (const float*)d_in[31];
  const float* dec_w3 = (const float*)d_in[32]; const float* dec_b3 = (const float*)d_in[33];
  float* out = (float*)d_out;

  const int N = in_sizes[0] / 32;
  const int E = in_sizes[2] / 8;
  const int L = in_sizes[19] / (128*128);
  const int* src = eidx;
  const int* dst = eidx + E;
  (void)n_in; (void)out_size;

  // ---- workspace carve, bounded by ws_size ----
  size_t off = 0;
  auto carve = [&](size_t bytes) -> char* {
    char* r = (char*)d_ws + off;
    off += (bytes + 255) & ~(size_t)255;
    return r;
  };
  float* y      = (float*)carve((size_t)N * 128 * 4);   // 25.6 MB
  u16*   xl     = (u16*)  carve((size_t)N * 128 * 2);   // 12.8 MB
  u16*   xr     = (u16*)  carve((size_t)N * 128 * 2);   // 12.8 MB
  float* sbuf   = (float*)carve((size_t)E * 4);         //  3.2 MB
  int*   rowptr = (int*)  carve((size_t)(N + 1) * 4);
  int*   eidbuf = (int*)  carve((size_t)E * 4);         //  3.2 MB
  int*   cnt    = (int*)  carve((size_t)N * 4);
  int*   cursor = (int*)  carve((size_t)N * 4);
  const size_t fixedBytes = off;

  if (ws_size < fixedBytes + (size_t)4096 * 256) {
    hipLaunchKernelGGL(zero_out_kernel, dim3(256), dim3(256), 0, stream, out, (long)N*2);
    return;
  }
  const size_t eaCapEdges = (ws_size - fixedBytes) / 256;  // bytes per bf16 row = 256
  u16* eaBuf = (u16*)((char*)d_ws + fixedBytes);
  const bool full = eaCapEdges >= (size_t)E;
  const int Ec = full ? E : (int)(eaCapEdges & ~(size_t)1023);

  // ---- node encoder + CSR build (dst is layer-invariant) ----
  hipLaunchKernelGGL(node_enc_kernel, dim3(1024), dim3(256), 0, stream,
                     x, enc_w1, enc_b1, enc_w2, enc_b2, enc_w3, enc_b3,
                     enc_lg, enc_lb, y, N);
  hipMemsetAsync(cnt, 0, (size_t)N * 4, stream);
  hipMemsetAsync(cursor, 0, (size_t)N * 4, stream);
  hipLaunchKernelGGL(csr_count_kernel, dim3(1024), dim3(256), 0, stream, dst, cnt, E);
  hipLaunchKernelGGL(csr_scan_kernel, dim3(1), dim3(1024), 0, stream, cnt, rowptr, N);
  hipLaunchKernelGGL(csr_fill_kernel, dim3(1024), dim3(256), 0, stream, dst, rowptr, cursor, eidbuf, E);

  if (full) {
    hipLaunchKernelGGL(edge_enc_kernel, dim3(2048), dim3(256), 0, stream,
                       edge_attr, ee_w1, ee_b1, ee_w2, ee_b2, ee_w3, ee_b3,
                       ee_lg, ee_lb, eaBuf, E);
  }

  for (int l = 0; l < L; ++l) {
    const float* wl = gat_wl + (size_t)l*128*128;
    const float* bl = gat_bl + (size_t)l*128;
    const float* wr = gat_wr + (size_t)l*128*128;
    const float* br = gat_br + (size_t)l*128;
    const float* we = gat_we + (size_t)l*128*128;
    const float* at = gat_att + (size_t)l*128;
    const float* bi = gat_bias + (size_t)l*128;
    const float* lg = ln_g + (size_t)l*128;
    const float* lb = ln_b + (size_t)l*128;

    hipLaunchKernelGGL(linear128_kernel, dim3(1024), dim3(256), 0, stream, y, wl, bl, xl, N);
    hipLaunchKernelGGL(linear128_kernel, dim3(1024), dim3(256), 0, stream, y, wr, br, xr, N);

    if (full) {
      hipLaunchKernelGGL(gat_logit_kernel, dim3(2048), dim3(256), 0, stream,
                         eaBuf, xl, xr, src, dst, we, at, sbuf, 0, E);
    } else {
      for (int eoff = 0; eoff < E; eoff += Ec) {
        const int c = (E - eoff < Ec) ? (E - eoff) : Ec;
        hipLaunchKernelGGL(edge_enc_kernel, dim3(2048), dim3(256), 0, stream,
                           edge_attr + (size_t)eoff*8, ee_w1, ee_b1, ee_w2, ee_b2,
                           ee_w3, ee_b3, ee_lg, ee_lb, eaBuf, c);
        hipLaunchKernelGGL(gat_logit_kernel, dim3(2048), dim3(256), 0, stream,
                           eaBuf, xl, xr, src, dst, we, at, sbuf, eoff, c);
      }
    }

    hipLaunchKernelGGL(gat_agg_kernel, dim3(1024), dim3(256), 0, stream,
                       sbuf, src, rowptr, eidbuf, xl, bi, lg, lb, y, N);
  }

  hipLaunchKernelGGL(decoder_kernel, dim3(512), dim3(256), 0, stream,
                     y, dec_w1, dec_b1, dec_w2, dec_b2, dec_w3, dec_b3, out, N);
}

// Round 5
// 4924.577 us; speedup vs baseline: 1.7283x; 1.7283x over previous
//
#include <hip/hip_runtime.h>

// ---------------------------------------------------------------------------
// GN_NN_32873679684148: encoder MLP+LN -> 4x GATv2+LN residual -> decoder MLP
// Round 4: fix NaN from round 3's MFMA kernels — intra-wave LDS RAW/WAR race
// (ds_write by one lane, ds_read by another, no fence). Added explicit
// lgkmcnt(0)+sched_barrier fences around per-wave LDS phases.
// N=50000, E=800000, H=128, L=4.
// ---------------------------------------------------------------------------

typedef unsigned short u16;
typedef unsigned int   u32;
typedef __attribute__((ext_vector_type(8))) short bf16x8;
typedef __attribute__((ext_vector_type(4))) float f32x4;

#define LEAKY01(a) ((a) > 0.f ? (a) : 0.01f*(a))
#define LEAKY20(a) ((a) > 0.f ? (a) : 0.2f*(a))

__device__ __forceinline__ float bf2f(u16 h) { return __uint_as_float(((u32)h) << 16); }
__device__ __forceinline__ u16 f2bf(float f) {
  u32 u = __float_as_uint(f);
  u32 r = u + 0x7fffu + ((u >> 16) & 1u);   // round-to-nearest-even
  return (u16)(r >> 16);
}
__device__ __forceinline__ float bflo(u32 p) { return __uint_as_float(p << 16); }
__device__ __forceinline__ float bfhi(u32 p) { return __uint_as_float(p & 0xffff0000u); }
__device__ __forceinline__ u32 packbf(float a, float b) {
  return (u32)f2bf(a) | ((u32)f2bf(b) << 16);
}

// fence between per-wave LDS write phase and read phase (intra-wave xlane)
__device__ __forceinline__ void lds_rw_fence() {
  __builtin_amdgcn_sched_barrier(0);
  asm volatile("s_waitcnt lgkmcnt(0)" ::: "memory");
  __builtin_amdgcn_sched_barrier(0);
}
// end-of-iteration fence: next iter's LDS writes must not hoist above reads
__device__ __forceinline__ void loop_mem_fence() {
  __builtin_amdgcn_sched_barrier(0);
  asm volatile("" ::: "memory");
}

// ---------------- node encoder: 32 -> 64 -> 96 -> 128 + LN -----------------
__global__ __launch_bounds__(256) void node_enc_kernel(
    const float* __restrict__ x,
    const float* __restrict__ w1, const float* __restrict__ b1,
    const float* __restrict__ w2, const float* __restrict__ b2,
    const float* __restrict__ w3, const float* __restrict__ b3,
    const float* __restrict__ g, const float* __restrict__ bb,
    float* __restrict__ y, int n)
{
  __shared__ float sw1t[32*64];
  __shared__ u32   sw2p[64*64];
  __shared__ u32   sw3p[96*64];
  const int tid = threadIdx.x;
  for (int i = tid; i < 32*64; i += 256) { int k = i >> 6, c = i & 63; sw1t[i] = w1[c*32 + k]; }
  for (int i = tid; i < 64*64; i += 256) { int k = i >> 6, l = i & 63; sw2p[i] = packbf(w2[l*64 + k], w2[(64 + (l & 31))*64 + k]); }
  for (int i = tid; i < 96*64; i += 256) { int k = i >> 6, l = i & 63; sw3p[i] = packbf(w3[l*96 + k], w3[(l + 64)*96 + k]); }
  __syncthreads();
  const int lane = tid & 63, wv = tid >> 6;
  const float b2a = b2[lane], b2b = b2[64 + (lane & 31)];
  const float b3a = b3[lane], b3b = b3[lane + 64];
  const float ga = g[lane], gb = g[lane + 64];
  const float ba = bb[lane], bbv = bb[lane + 64];
  for (long row = (long)blockIdx.x*4 + wv; row < n; row += (long)gridDim.x*4) {
    float xin[32];
    const float4* xp = (const float4*)(x + row*32);
    #pragma unroll
    for (int q = 0; q < 8; ++q) ((float4*)xin)[q] = xp[q];
    float h1 = b1[lane];
    #pragma unroll
    for (int k = 0; k < 32; ++k) h1 += xin[k] * sw1t[k*64 + lane];
    h1 = LEAKY01(h1);
    float a0 = b2a, a1 = b2b;
    #pragma unroll
    for (int k = 0; k < 64; ++k) {
      const u32 wp = sw2p[k*64 + lane];
      const float hv = __shfl(h1, k, 64);
      a0 += hv * bflo(wp); a1 += hv * bfhi(wp);
    }
    const float h2a = LEAKY01(a0), h2b = LEAKY01(a1);
    float o0 = b3a, o1 = b3b;
    #pragma unroll
    for (int k = 0; k < 64; ++k) {
      const u32 wp = sw3p[k*64 + lane];
      const float hv = __shfl(h2a, k, 64);
      o0 += hv * bflo(wp); o1 += hv * bfhi(wp);
    }
    #pragma unroll
    for (int k = 0; k < 32; ++k) {
      const u32 wp = sw3p[(64 + k)*64 + lane];
      const float hv = __shfl(h2b, k, 64);
      o0 += hv * bflo(wp); o1 += hv * bfhi(wp);
    }
    float sum = o0 + o1, sq = o0*o0 + o1*o1;
    for (int off = 32; off; off >>= 1) { sum += __shfl_xor(sum, off, 64); sq += __shfl_xor(sq, off, 64); }
    const float mu = sum * (1.f/128.f);
    const float var = sq * (1.f/128.f) - mu*mu;
    const float rs = rsqrtf(var + 1e-5f);
    y[row*128 + lane]      = (o0 - mu) * rs * ga + ba;
    y[row*128 + lane + 64] = (o1 - mu) * rs * gb + bbv;
  }
}

// ------- edge encoder: 8 -> 48 -> 88 -> 128 + LN, 2 rows/wave, bf16 out ----
__global__ __launch_bounds__(256) void edge_enc_kernel(
    const float* __restrict__ eat,
    const float* __restrict__ w1, const float* __restrict__ b1,
    const float* __restrict__ w2, const float* __restrict__ b2,
    const float* __restrict__ w3, const float* __restrict__ b3,
    const float* __restrict__ g, const float* __restrict__ bb,
    u16* __restrict__ ea, int ecnt)
{
  __shared__ float sw1t[8*48];
  __shared__ u32   sw2p[48*64];
  __shared__ u32   sw3p[88*64];
  const int tid = threadIdx.x;
  for (int i = tid; i < 8*48; i += 256)  { int k = i/48, c = i - k*48; sw1t[i] = w1[c*8 + k]; }
  for (int i = tid; i < 48*64; i += 256) { int k = i >> 6, l = i & 63; sw2p[i] = packbf(w2[l*48 + k], w2[(64 + (l % 24))*48 + k]); }
  for (int i = tid; i < 88*64; i += 256) { int k = i >> 6, l = i & 63; sw3p[i] = packbf(w3[l*88 + k], w3[(l + 64)*88 + k]); }
  __syncthreads();
  const int lane = tid & 63, wv = tid >> 6;
  const int c48 = lane % 48;
  const float b1v = b1[c48];
  const float b2a = b2[lane], b2b = b2[64 + (lane % 24)];
  const float b3a = b3[lane], b3b = b3[lane + 64];
  const float ga = g[lane], gb = g[lane + 64];
  const float ba = bb[lane], bbv = bb[lane + 64];
  const long stride = (long)gridDim.x * 4 * 2;
  for (long r0 = ((long)blockIdx.x*4 + wv)*2; r0 < ecnt; r0 += stride) {
    const long r1 = r0 + 1;
    const bool v1 = r1 < ecnt;
    float xin0[8], xin1[8];
    const float4* p0 = (const float4*)(eat + r0*8);
    ((float4*)xin0)[0] = p0[0]; ((float4*)xin0)[1] = p0[1];
    if (v1) {
      const float4* p1 = (const float4*)(eat + r1*8);
      ((float4*)xin1)[0] = p1[0]; ((float4*)xin1)[1] = p1[1];
    } else {
      #pragma unroll
      for (int q = 0; q < 8; ++q) xin1[q] = 0.f;
    }
    float h1_0 = b1v, h1_1 = b1v;
    #pragma unroll
    for (int k = 0; k < 8; ++k) {
      const float w = sw1t[k*48 + c48];
      h1_0 += xin0[k]*w; h1_1 += xin1[k]*w;
    }
    h1_0 = LEAKY01(h1_0); h1_1 = LEAKY01(h1_1);
    float a00 = b2a, a01 = b2b, a10 = b2a, a11 = b2b;
    #pragma unroll
    for (int k = 0; k < 48; ++k) {
      const u32 wp = sw2p[k*64 + lane];
      const float wl = bflo(wp), wh = bfhi(wp);
      const float h0 = __shfl(h1_0, k, 64);
      const float h1v = __shfl(h1_1, k, 64);
      a00 += h0*wl; a01 += h0*wh;
      a10 += h1v*wl; a11 += h1v*wh;
    }
    const float h2a0 = LEAKY01(a00), h2b0 = LEAKY01(a01);
    const float h2a1 = LEAKY01(a10), h2b1 = LEAKY01(a11);
    float o00 = b3a, o01 = b3b, o10 = b3a, o11 = b3b;
    #pragma unroll
    for (int k = 0; k < 64; ++k) {
      const u32 wp = sw3p[k*64 + lane];
      const float wl = bflo(wp), wh = bfhi(wp);
      const float h0 = __shfl(h2a0, k, 64);
      const float h1v = __shfl(h2a1, k, 64);
      o00 += h0*wl; o01 += h0*wh;
      o10 += h1v*wl; o11 += h1v*wh;
    }
    #pragma unroll
    for (int k = 0; k < 24; ++k) {
      const u32 wp = sw3p[(64 + k)*64 + lane];
      const float wl = bflo(wp), wh = bfhi(wp);
      const float h0 = __shfl(h2b0, k, 64);
      const float h1v = __shfl(h2b1, k, 64);
      o00 += h0*wl; o01 += h0*wh;
      o10 += h1v*wl; o11 += h1v*wh;
    }
    float s0 = o00 + o01, q0 = o00*o00 + o01*o01;
    float s1 = o10 + o11, q1 = o10*o10 + o11*o11;
    for (int off = 32; off; off >>= 1) {
      s0 += __shfl_xor(s0, off, 64); q0 += __shfl_xor(q0, off, 64);
      s1 += __shfl_xor(s1, off, 64); q1 += __shfl_xor(q1, off, 64);
    }
    {
      const float mu = s0 * (1.f/128.f);
      const float var = q0 * (1.f/128.f) - mu*mu;
      const float rs = rsqrtf(var + 1e-5f);
      u16* er = ea + r0*128;
      er[lane]      = f2bf((o00 - mu) * rs * ga + ba);
      er[lane + 64] = f2bf((o01 - mu) * rs * gb + bbv);
    }
    if (v1) {
      const float mu = s1 * (1.f/128.f);
      const float var = q1 * (1.f/128.f) - mu*mu;
      const float rs = rsqrtf(var + 1e-5f);
      u16* er = ea + r1*128;
      er[lane]      = f2bf((o10 - mu) * rs * ga + ba);
      er[lane + 64] = f2bf((o11 - mu) * rs * gb + bbv);
    }
  }
}

// --------- MFMA linear 128x128: out(bf16) = in(fp32) @ w.T + b ------------
__global__ __launch_bounds__(256, 2) void linear128_mfma(
    const float* __restrict__ in, const float* __restrict__ w,
    const float* __restrict__ b, u16* __restrict__ out, int n)
{
  __shared__ u16 sh_t[4][16][136];   // per-wave transpose buffer
  const int tid = threadIdx.x;
  const int lane = tid & 63, wv = tid >> 6;
  const int c16 = lane & 15, g = lane >> 4;
  bf16x8 bw[8][4];
  #pragma unroll
  for (int tc = 0; tc < 8; ++tc) {
    #pragma unroll
    for (int t = 0; t < 4; ++t) {
      const float* wp = w + (tc*16 + c16)*128 + t*32 + g*8;
      bf16x8 v;
      #pragma unroll
      for (int j = 0; j < 8; ++j) v[j] = (short)f2bf(wp[j]);
      bw[tc][t] = v;
    }
  }
  float bv[8];
  #pragma unroll
  for (int tc = 0; tc < 8; ++tc) bv[tc] = b[tc*16 + c16];

  const int nt = (n + 15) >> 4;
  const long wid = (long)blockIdx.x*4 + wv;
  const long wstride = (long)gridDim.x*4;
  for (long tile = wid; tile < nt; tile += wstride) {
    const long r0 = tile << 4;
    const long rowA = (r0 + c16 < n) ? (r0 + c16) : (n - 1);
    bf16x8 af[4];
    #pragma unroll
    for (int t = 0; t < 4; ++t) {
      const float* ip = in + rowA*128 + t*32 + g*8;
      const float4 v0 = *(const float4*)ip;
      const float4 v1 = *(const float4*)(ip + 4);
      bf16x8 a;
      a[0] = (short)f2bf(v0.x); a[1] = (short)f2bf(v0.y);
      a[2] = (short)f2bf(v0.z); a[3] = (short)f2bf(v0.w);
      a[4] = (short)f2bf(v1.x); a[5] = (short)f2bf(v1.y);
      a[6] = (short)f2bf(v1.z); a[7] = (short)f2bf(v1.w);
      af[t] = a;
    }
    #pragma unroll
    for (int tc = 0; tc < 8; ++tc) {
      f32x4 acc = {0.f, 0.f, 0.f, 0.f};
      #pragma unroll
      for (int t = 0; t < 4; ++t)
        acc = __builtin_amdgcn_mfma_f32_16x16x32_bf16(af[t], bw[tc][t], acc, 0, 0, 0);
      #pragma unroll
      for (int j = 0; j < 4; ++j)
        sh_t[wv][g*4 + j][tc*16 + c16] = f2bf(acc[j] + bv[tc]);
    }
    lds_rw_fence();            // LDS writes above must land before xlane reads
    #pragma unroll 4
    for (int r = 0; r < 16; ++r) {
      const long grow = r0 + r;
      if (grow < n) {
        const u32 vv = *(const u32*)&sh_t[wv][r][2*lane];
        ((u32*)out)[grow*64 + lane] = vv;
      }
    }
    loop_mem_fence();          // next iter's writes must not hoist above reads
  }
}

// ------ MFMA fused logit: s = leaky(ea@we.T + xl[src]+xr[dst], .2) . att ---
__global__ __launch_bounds__(256, 2) void gat_logit_mfma(
    const u16* __restrict__ ea,         // chunk base (local rows)
    const u16* __restrict__ xl, const u16* __restrict__ xr,
    const int* __restrict__ src, const int* __restrict__ dst,
    const float* __restrict__ we, const float* __restrict__ att,
    float* __restrict__ s_out, int eoff, int ecnt, int E)
{
  __shared__ float sh_g[4][16][132];   // per-wave xl[src]+xr[dst] (f32)
  const int tid = threadIdx.x;
  const int lane = tid & 63, wv = tid >> 6;
  const int c16 = lane & 15, g = lane >> 4;
  bf16x8 bw[8][4];
  #pragma unroll
  for (int tc = 0; tc < 8; ++tc) {
    #pragma unroll
    for (int t = 0; t < 4; ++t) {
      const float* wp = we + (tc*16 + c16)*128 + t*32 + g*8;
      bf16x8 v;
      #pragma unroll
      for (int j = 0; j < 8; ++j) v[j] = (short)f2bf(wp[j]);
      bw[tc][t] = v;
    }
  }
  float attv[8];
  #pragma unroll
  for (int tc = 0; tc < 8; ++tc) attv[tc] = att[tc*16 + c16];

  const u32* xl32 = (const u32*)xl;
  const u32* xr32 = (const u32*)xr;
  const int nt = (ecnt + 15) >> 4;
  const long wid = (long)blockIdx.x*4 + wv;
  const long wstride = (long)gridDim.x*4;
  for (long tile = wid; tile < nt; tile += wstride) {
    const long i0 = tile << 4;          // local row base
    const long e0 = eoff + i0;          // global edge base
    int sv = 0, dv = 0;
    if (lane < 16) {
      const long eg = (e0 + lane < E) ? (e0 + lane) : (E - 1);
      sv = src[eg]; dv = dst[eg];
    }
    #pragma unroll 4
    for (int e = 0; e < 16; ++e) {
      const int srow = __shfl(sv, e, 64);
      const int drow = __shfl(dv, e, 64);
      const u32 xa = xl32[(long)srow*64 + lane];
      const u32 xb = xr32[(long)drow*64 + lane];
      float2 sg;
      sg.x = bflo(xa) + bflo(xb);
      sg.y = bfhi(xa) + bfhi(xb);
      *(float2*)&sh_g[wv][e][lane*2] = sg;
    }
    lds_rw_fence();            // gather writes must land before xlane reads
    const long rA = (i0 + c16 < ecnt) ? (i0 + c16) : (ecnt - 1);
    bf16x8 af[4];
    #pragma unroll
    for (int t = 0; t < 4; ++t)
      af[t] = *(const bf16x8*)(ea + rA*128 + t*32 + g*8);
    float p0 = 0.f, p1 = 0.f, p2 = 0.f, p3 = 0.f;
    #pragma unroll
    for (int tc = 0; tc < 8; ++tc) {
      f32x4 acc = {0.f, 0.f, 0.f, 0.f};
      #pragma unroll
      for (int t = 0; t < 4; ++t)
        acc = __builtin_amdgcn_mfma_f32_16x16x32_bf16(af[t], bw[tc][t], acc, 0, 0, 0);
      const float av = attv[tc];
      #pragma unroll
      for (int j = 0; j < 4; ++j) {
        float ev = acc[j] + sh_g[wv][g*4 + j][tc*16 + c16];
        ev = LEAKY20(ev);
        const float term = ev * av;
        if (j == 0) p0 += term; else if (j == 1) p1 += term;
        else if (j == 2) p2 += term; else p3 += term;
      }
    }
    #pragma unroll
    for (int off = 1; off <= 8; off <<= 1) {
      p0 += __shfl_xor(p0, off, 64);
      p1 += __shfl_xor(p1, off, 64);
      p2 += __shfl_xor(p2, off, 64);
      p3 += __shfl_xor(p3, off, 64);
    }
    if (c16 == 0) {
      const long rbase = e0 + g*4;
      if (rbase + 0 < E && i0 + g*4 + 0 < ecnt) s_out[rbase + 0] = p0;
      if (rbase + 1 < E && i0 + g*4 + 1 < ecnt) s_out[rbase + 1] = p1;
      if (rbase + 2 < E && i0 + g*4 + 2 < ecnt) s_out[rbase + 2] = p2;
      if (rbase + 3 < E && i0 + g*4 + 3 < ecnt) s_out[rbase + 3] = p3;
    }
    loop_mem_fence();          // next iter's writes must not hoist above reads
  }
}

// ---------------- CSR build ----------------
__global__ __launch_bounds__(256) void csr_count_kernel(
    const int* __restrict__ dst, int* __restrict__ cnt, int E)
{
  for (long e = (long)blockIdx.x*blockDim.x + threadIdx.x; e < E;
       e += (long)gridDim.x*blockDim.x)
    atomicAdd(&cnt[dst[e]], 1);
}

__global__ __launch_bounds__(1024) void csr_scan_kernel(
    const int* __restrict__ cnt, int* __restrict__ rowptr, int n)
{
  __shared__ int part[1024];
  const int t = threadIdx.x;
  const int chunk = (n + 1023) >> 10;
  const int b = t * chunk;
  const int e = min(b + chunk, n);
  int s = 0;
  for (int i = b; i < e; ++i) s += cnt[i];
  part[t] = s;
  __syncthreads();
  for (int d = 1; d < 1024; d <<= 1) {
    int v = (t >= d) ? part[t - d] : 0;
    __syncthreads();
    if (t >= d) part[t] += v;
    __syncthreads();
  }
  int pre = (t == 0) ? 0 : part[t - 1];
  for (int i = b; i < e; ++i) { rowptr[i] = pre; pre += cnt[i]; }
  if (t == 1023) rowptr[n] = pre;
}

__global__ __launch_bounds__(256) void csr_fill_kernel(
    const int* __restrict__ dst, const int* __restrict__ rowptr,
    int* __restrict__ cursor, int* __restrict__ eid, int E)
{
  for (long e = (long)blockIdx.x*blockDim.x + threadIdx.x; e < E;
       e += (long)gridDim.x*blockDim.x) {
    const int d = dst[e];
    const int pos = atomicAdd(&cursor[d], 1);
    eid[rowptr[d] + pos] = (int)e;
  }
}

// ---- per-node: softmax over CSR edges + weighted gather + LN residual ----
__global__ __launch_bounds__(256) void gat_agg_kernel(
    const float* __restrict__ s, const int* __restrict__ src,
    const int* __restrict__ rowptr, const int* __restrict__ eid,
    const u16* __restrict__ xl, const float* __restrict__ bias,
    const float* __restrict__ g, const float* __restrict__ bb,
    float* __restrict__ y, int n)
{
  const int tid = threadIdx.x;
  const int lane = tid & 63, wv = tid >> 6;
  const int wpb = blockDim.x >> 6;
  const float bi0 = bias[lane], bi1 = bias[lane + 64];
  const float g0 = g[lane], g1 = g[lane + 64];
  const float bb0 = bb[lane], bb1 = bb[lane + 64];
  for (long node = (long)blockIdx.x*wpb + wv; node < n; node += (long)gridDim.x*wpb) {
    const int beg = rowptr[node], end = rowptr[node + 1];
    float m = -INFINITY;
    for (int j = beg; j < end; ++j) m = fmaxf(m, s[eid[j]]);
    float den = 0.f, a0 = 0.f, a1 = 0.f;
    for (int j = beg; j < end; ++j) {
      const int e = eid[j];
      const float z = __expf(s[e] - m);
      den += z;
      const int sN = src[e];
      a0 += z * bf2f(xl[(long)sN*128 + lane]);
      a1 += z * bf2f(xl[(long)sN*128 + lane + 64]);
    }
    const float inv = 1.f / fmaxf(den, 1e-16f);
    const float v0 = a0*inv + bi0;
    const float v1 = a1*inv + bi1;
    float sum = v0 + v1, sq = v0*v0 + v1*v1;
    for (int off = 32; off; off >>= 1) { sum += __shfl_xor(sum, off, 64); sq += __shfl_xor(sq, off, 64); }
    const float mu = sum * (1.f/128.f);
    const float var = sq * (1.f/128.f) - mu*mu;
    const float rs = rsqrtf(var + 1e-5f);
    y[node*128 + lane]      += (v0 - mu) * rs * g0 + bb0;
    y[node*128 + lane + 64] += (v1 - mu) * rs * g1 + bb1;
  }
}

// ---------------- decoder: 128 -> 86 -> 44 -> 2, wave-per-row ----------------
__global__ __launch_bounds__(256) void decoder_kernel(
    const float* __restrict__ y,
    const float* __restrict__ w1, const float* __restrict__ b1,
    const float* __restrict__ w2, const float* __restrict__ b2,
    const float* __restrict__ w3, const float* __restrict__ b3,
    float* __restrict__ out, int n)
{
  __shared__ u32   sw1p[128*64];
  __shared__ float sw2t[86*64];
  const int tid = threadIdx.x;
  for (int i = tid; i < 128*64; i += 256) {
    int k = i >> 6, l = i & 63;
    sw1p[i] = packbf(w1[l*128 + k], w1[(64 + (l % 22))*128 + k]);
  }
  for (int i = tid; i < 86*64; i += 256) {
    int k = i >> 6, l = i & 63;
    sw2t[i] = w2[(l % 44)*86 + k];
  }
  __syncthreads();
  const int lane = tid & 63, wv = tid >> 6;
  const float b1a = b1[lane], b1b = b1[64 + (lane % 22)];
  const float b2v = b2[lane % 44];
  const float w3a = (lane < 44) ? w3[lane] : 0.f;
  const float w3b = (lane < 44) ? w3[44 + lane] : 0.f;
  const float b3a = b3[0], b3b = b3[1];
  for (long row = (long)blockIdx.x*4 + wv; row < n; row += (long)gridDim.x*4) {
    const float ya = y[row*128 + lane];
    const float yb = y[row*128 + lane + 64];
    float a0 = b1a, a1 = b1b;
    #pragma unroll
    for (int k = 0; k < 64; ++k) {
      const u32 wp = sw1p[k*64 + lane];
      const float hv = __shfl(ya, k, 64);
      a0 += hv * bflo(wp); a1 += hv * bfhi(wp);
    }
    #pragma unroll
    for (int k = 0; k < 64; ++k) {
      const u32 wp = sw1p[(64 + k)*64 + lane];
      const float hv = __shfl(yb, k, 64);
      a0 += hv * bflo(wp); a1 += hv * bfhi(wp);
    }
    const float h1a = LEAKY01(a0), h1b = LEAKY01(a1);
    float a2 = b2v;
    #pragma unroll
    for (int k = 0; k < 64; ++k) {
      const float hv = __shfl(h1a, k, 64);
      a2 += hv * sw2t[k*64 + lane];
    }
    #pragma unroll
    for (int k = 0; k < 22; ++k) {
      const float hv = __shfl(h1b, k, 64);
      a2 += hv * sw2t[(64 + k)*64 + lane];
    }
    const float h2 = LEAKY01(a2);
    float t0 = (lane < 44) ? h2 * w3a : 0.f;
    float t1 = (lane < 44) ? h2 * w3b : 0.f;
    for (int off = 32; off; off >>= 1) { t0 += __shfl_xor(t0, off, 64); t1 += __shfl_xor(t1, off, 64); }
    if (lane == 0) {
      out[row*2]     = t0 + b3a;
      out[row*2 + 1] = t1 + b3b;
    }
  }
}

__global__ __launch_bounds__(256) void zero_out_kernel(float* __restrict__ out, long n)
{
  for (long i = (long)blockIdx.x*blockDim.x + threadIdx.x; i < n;
       i += (long)gridDim.x*blockDim.x) out[i] = 0.f;
}

// ---------------------------------------------------------------------------
extern "C" void kernel_launch(void* const* d_in, const int* in_sizes, int n_in,
                              void* d_out, int out_size, void* d_ws, size_t ws_size,
                              hipStream_t stream) {
  const float* x        = (const float*)d_in[0];
  const int*   eidx     = (const int*)  d_in[1];
  const float* edge_attr= (const float*)d_in[2];
  const float* enc_w1 = (const float*)d_in[3];  const float* enc_b1 = (const float*)d_in[4];
  const float* enc_w2 = (const float*)d_in[5];  const float* enc_b2 = (const float*)d_in[6];
  const float* enc_w3 = (const float*)d_in[7];  const float* enc_b3 = (const float*)d_in[8];
  const float* enc_lg = (const float*)d_in[9];  const float* enc_lb = (const float*)d_in[10];
  const float* ee_w1  = (const float*)d_in[11]; const float* ee_b1  = (const float*)d_in[12];
  const float* ee_w2  = (const float*)d_in[13]; const float* ee_b2  = (const float*)d_in[14];
  const float* ee_w3  = (const float*)d_in[15]; const float* ee_b3  = (const float*)d_in[16];
  const float* ee_lg  = (const float*)d_in[17]; const float* ee_lb  = (const float*)d_in[18];
  const float* gat_wl = (const float*)d_in[19]; const float* gat_bl = (const float*)d_in[20];
  const float* gat_wr = (const float*)d_in[21]; const float* gat_br = (const float*)d_in[22];
  const float* gat_we = (const float*)d_in[23]; const float* gat_att= (const float*)d_in[24];
  const float* gat_bias=(const float*)d_in[25];
  const float* ln_g   = (const float*)d_in[26]; const float* ln_b   = (const float*)d_in[27];
  const float* dec_w1 = (const float*)d_in[28]; const float* dec_b1 = (const float*)d_in[29];
  const float* dec_w2 = (const float*)d_in[30]; const float* dec_b2 = (const float*)d_in[31];
  const float* dec_w3 = (const float*)d_in[32]; const float* dec_b3 = (const float*)d_in[33];
  float* out = (float*)d_out;

  const int N = in_sizes[0] / 32;
  const int E = in_sizes[2] / 8;
  const int L = in_sizes[19] / (128*128);
  const int* src = eidx;
  const int* dst = eidx + E;
  (void)n_in; (void)out_size;

  size_t off = 0;
  auto carve = [&](size_t bytes) -> char* {
    char* r = (char*)d_ws + off;
    off += (bytes + 255) & ~(size_t)255;
    return r;
  };
  float* y      = (float*)carve((size_t)N * 128 * 4);
  u16*   xl     = (u16*)  carve((size_t)N * 128 * 2);
  u16*   xr     = (u16*)  carve((size_t)N * 128 * 2);
  float* sbuf   = (float*)carve((size_t)E * 4);
  int*   rowptr = (int*)  carve((size_t)(N + 1) * 4);
  int*   eidbuf = (int*)  carve((size_t)E * 4);
  int*   cnt    = (int*)  carve((size_t)N * 4);
  int*   cursor = (int*)  carve((size_t)N * 4);
  const size_t fixedBytes = off;

  if (ws_size < fixedBytes + (size_t)4096 * 256) {
    hipLaunchKernelGGL(zero_out_kernel, dim3(256), dim3(256), 0, stream, out, (long)N*2);
    return;
  }
  const size_t eaCapEdges = (ws_size - fixedBytes) / 256;
  u16* eaBuf = (u16*)((char*)d_ws + fixedBytes);
  const bool full = eaCapEdges >= (size_t)E;
  const int Ec = full ? E : (int)(eaCapEdges & ~(size_t)1023);

  hipLaunchKernelGGL(node_enc_kernel, dim3(1024), dim3(256), 0, stream,
                     x, enc_w1, enc_b1, enc_w2, enc_b2, enc_w3, enc_b3,
                     enc_lg, enc_lb, y, N);
  hipMemsetAsync(cnt, 0, (size_t)N * 4, stream);
  hipMemsetAsync(cursor, 0, (size_t)N * 4, stream);
  hipLaunchKernelGGL(csr_count_kernel, dim3(1024), dim3(256), 0, stream, dst, cnt, E);
  hipLaunchKernelGGL(csr_scan_kernel, dim3(1), dim3(1024), 0, stream, cnt, rowptr, N);
  hipLaunchKernelGGL(csr_fill_kernel, dim3(1024), dim3(256), 0, stream, dst, rowptr, cursor, eidbuf, E);

  if (full) {
    hipLaunchKernelGGL(edge_enc_kernel, dim3(2048), dim3(256), 0, stream,
                       edge_attr, ee_w1, ee_b1, ee_w2, ee_b2, ee_w3, ee_b3,
                       ee_lg, ee_lb, eaBuf, E);
  }

  const int linGrid = ((N + 15) / 16 + 3) / 4;   // one 16-row tile per wave
  for (int l = 0; l < L; ++l) {
    const float* wl = gat_wl + (size_t)l*128*128;
    const float* bl = gat_bl + (size_t)l*128;
    const float* wr = gat_wr + (size_t)l*128*128;
    const float* br = gat_br + (size_t)l*128;
    const float* we = gat_we + (size_t)l*128*128;
    const float* at = gat_att + (size_t)l*128;
    const float* bi = gat_bias + (size_t)l*128;
    const float* lg = ln_g + (size_t)l*128;
    const float* lb = ln_b + (size_t)l*128;

    hipLaunchKernelGGL(linear128_mfma, dim3(linGrid), dim3(256), 0, stream, y, wl, bl, xl, N);
    hipLaunchKernelGGL(linear128_mfma, dim3(linGrid), dim3(256), 0, stream, y, wr, br, xr, N);

    if (full) {
      hipLaunchKernelGGL(gat_logit_mfma, dim3(1024), dim3(256), 0, stream,
                         eaBuf, xl, xr, src, dst, we, at, sbuf, 0, E, E);
    } else {
      for (int eoff = 0; eoff < E; eoff += Ec) {
        const int c = (E - eoff < Ec) ? (E - eoff) : Ec;
        hipLaunchKernelGGL(edge_enc_kernel, dim3(2048), dim3(256), 0, stream,
                           edge_attr + (size_t)eoff*8, ee_w1, ee_b1, ee_w2, ee_b2,
                           ee_w3, ee_b3, ee_lg, ee_lb, eaBuf, c);
        hipLaunchKernelGGL(gat_logit_mfma, dim3(1024), dim3(256), 0, stream,
                           eaBuf, xl, xr, src, dst, we, at, sbuf, eoff, c, E);
      }
    }

    hipLaunchKernelGGL(gat_agg_kernel, dim3(1024), dim3(256), 0, stream,
                       sbuf, src, rowptr, eidbuf, xl, bi, lg, lb, y, N);
  }

  hipLaunchKernelGGL(decoder_kernel, dim3(512), dim3(256), 0, stream,
                     y, dec_w1, dec_b1, dec_w2, dec_b2, dec_w3, dec_b3, out, N);
}

// Round 6
// 3041.430 us; speedup vs baseline: 2.7983x; 1.6192x over previous
//
#include <hip/hip_runtime.h>

// ---------------------------------------------------------------------------
// GN_NN_32873679684148: encoder MLP+LN -> 4x GATv2+LN residual -> decoder MLP
// Round 6: MFMA edge encoder (8->48->88->128+LN), one wave = 16 edges,
// layer chaining via per-wave LDS round trips with the round-4-proven fence
// pattern. Weight B-frags held in VGPRs. Everything else = round 5 (passed).
// N=50000, E=800000, H=128, L=4.
// ---------------------------------------------------------------------------

typedef unsigned short u16;
typedef unsigned int   u32;
typedef __attribute__((ext_vector_type(8))) short bf16x8;
typedef __attribute__((ext_vector_type(4))) float f32x4;

#define LEAKY01(a) ((a) > 0.f ? (a) : 0.01f*(a))
#define LEAKY20(a) ((a) > 0.f ? (a) : 0.2f*(a))

__device__ __forceinline__ float bf2f(u16 h) { return __uint_as_float(((u32)h) << 16); }
__device__ __forceinline__ u16 f2bf(float f) {
  u32 u = __float_as_uint(f);
  u32 r = u + 0x7fffu + ((u >> 16) & 1u);   // round-to-nearest-even
  return (u16)(r >> 16);
}
__device__ __forceinline__ float bflo(u32 p) { return __uint_as_float(p << 16); }
__device__ __forceinline__ float bfhi(u32 p) { return __uint_as_float(p & 0xffff0000u); }
__device__ __forceinline__ u32 packbf(float a, float b) {
  return (u32)f2bf(a) | ((u32)f2bf(b) << 16);
}

// fence between per-wave LDS write phase and read phase (intra-wave xlane)
__device__ __forceinline__ void lds_rw_fence() {
  __builtin_amdgcn_sched_barrier(0);
  asm volatile("s_waitcnt lgkmcnt(0)" ::: "memory");
  __builtin_amdgcn_sched_barrier(0);
}
// end-of-iteration fence: next iter's LDS writes must not hoist above reads
__device__ __forceinline__ void loop_mem_fence() {
  __builtin_amdgcn_sched_barrier(0);
  asm volatile("" ::: "memory");
}

// ---------------- node encoder: 32 -> 64 -> 96 -> 128 + LN -----------------
__global__ __launch_bounds__(256) void node_enc_kernel(
    const float* __restrict__ x,
    const float* __restrict__ w1, const float* __restrict__ b1,
    const float* __restrict__ w2, const float* __restrict__ b2,
    const float* __restrict__ w3, const float* __restrict__ b3,
    const float* __restrict__ g, const float* __restrict__ bb,
    float* __restrict__ y, int n)
{
  __shared__ float sw1t[32*64];
  __shared__ u32   sw2p[64*64];
  __shared__ u32   sw3p[96*64];
  const int tid = threadIdx.x;
  for (int i = tid; i < 32*64; i += 256) { int k = i >> 6, c = i & 63; sw1t[i] = w1[c*32 + k]; }
  for (int i = tid; i < 64*64; i += 256) { int k = i >> 6, l = i & 63; sw2p[i] = packbf(w2[l*64 + k], w2[(64 + (l & 31))*64 + k]); }
  for (int i = tid; i < 96*64; i += 256) { int k = i >> 6, l = i & 63; sw3p[i] = packbf(w3[l*96 + k], w3[(l + 64)*96 + k]); }
  __syncthreads();
  const int lane = tid & 63, wv = tid >> 6;
  const float b2a = b2[lane], b2b = b2[64 + (lane & 31)];
  const float b3a = b3[lane], b3b = b3[lane + 64];
  const float ga = g[lane], gb = g[lane + 64];
  const float ba = bb[lane], bbv = bb[lane + 64];
  for (long row = (long)blockIdx.x*4 + wv; row < n; row += (long)gridDim.x*4) {
    float xin[32];
    const float4* xp = (const float4*)(x + row*32);
    #pragma unroll
    for (int q = 0; q < 8; ++q) ((float4*)xin)[q] = xp[q];
    float h1 = b1[lane];
    #pragma unroll
    for (int k = 0; k < 32; ++k) h1 += xin[k] * sw1t[k*64 + lane];
    h1 = LEAKY01(h1);
    float a0 = b2a, a1 = b2b;
    #pragma unroll
    for (int k = 0; k < 64; ++k) {
      const u32 wp = sw2p[k*64 + lane];
      const float hv = __shfl(h1, k, 64);
      a0 += hv * bflo(wp); a1 += hv * bfhi(wp);
    }
    const float h2a = LEAKY01(a0), h2b = LEAKY01(a1);
    float o0 = b3a, o1 = b3b;
    #pragma unroll
    for (int k = 0; k < 64; ++k) {
      const u32 wp = sw3p[k*64 + lane];
      const float hv = __shfl(h2a, k, 64);
      o0 += hv * bflo(wp); o1 += hv * bfhi(wp);
    }
    #pragma unroll
    for (int k = 0; k < 32; ++k) {
      const u32 wp = sw3p[(64 + k)*64 + lane];
      const float hv = __shfl(h2b, k, 64);
      o0 += hv * bflo(wp); o1 += hv * bfhi(wp);
    }
    float sum = o0 + o1, sq = o0*o0 + o1*o1;
    for (int off = 32; off; off >>= 1) { sum += __shfl_xor(sum, off, 64); sq += __shfl_xor(sq, off, 64); }
    const float mu = sum * (1.f/128.f);
    const float var = sq * (1.f/128.f) - mu*mu;
    const float rs = rsqrtf(var + 1e-5f);
    y[row*128 + lane]      = (o0 - mu) * rs * ga + ba;
    y[row*128 + lane + 64] = (o1 - mu) * rs * gb + bbv;
  }
}

// -------- MFMA edge encoder: 8 -> 48 -> 88 -> 128 + LN, bf16 out ----------
// one wave = 16 edges; D->LDS->A round trip between layers (fenced).
__global__ __launch_bounds__(256, 2) void edge_enc_mfma(
    const float* __restrict__ eat,      // chunk base: ecnt rows of 8
    const float* __restrict__ w1, const float* __restrict__ b1,
    const float* __restrict__ w2, const float* __restrict__ b2,
    const float* __restrict__ w3, const float* __restrict__ b3,
    const float* __restrict__ g, const float* __restrict__ bb,
    u16* __restrict__ ea, int ecnt)
{
  __shared__ __align__(16) u16 h1buf[4][16][72];    // pitch 72 u16 = 144B
  __shared__ __align__(16) u16 h2buf[4][16][104];   // pitch 104 u16 = 208B
  __shared__ __align__(16) u16 obuf[4][16][136];    // pitch 136 u16 = 272B
  const int tid = threadIdx.x;
  const int lane = tid & 63, wv = tid >> 6;
  const int c16 = lane & 15, gq = lane >> 4;
  // zero whole h1/h2 buffers once: pad cols (>=48 / >=88) must read as 0 and
  // are never written afterwards.
  for (int i = tid; i < 4*16*72; i += 256)  ((u16*)h1buf)[i] = 0;
  for (int i = tid; i < 4*16*104; i += 256) ((u16*)h2buf)[i] = 0;
  __syncthreads();

  // ---- B-fragments in VGPRs (layouts identical to linear128_mfma) ----
  bf16x8 bw1[3];
  #pragma unroll
  for (int tc = 0; tc < 3; ++tc) {
    bf16x8 v;
    #pragma unroll
    for (int j = 0; j < 8; ++j) {
      const int k = gq*8 + j;
      v[j] = (k < 8) ? (short)f2bf(w1[(tc*16 + c16)*8 + k]) : (short)0;
    }
    bw1[tc] = v;
  }
  bf16x8 bw2[6][2];
  #pragma unroll
  for (int tc = 0; tc < 6; ++tc) {
    const int col = tc*16 + c16;
    #pragma unroll
    for (int t = 0; t < 2; ++t) {
      bf16x8 v;
      #pragma unroll
      for (int j = 0; j < 8; ++j) {
        const int k = t*32 + gq*8 + j;
        v[j] = (col < 88 && k < 48) ? (short)f2bf(w2[col*48 + k]) : (short)0;
      }
      bw2[tc][t] = v;
    }
  }
  bf16x8 bw3[8][3];
  #pragma unroll
  for (int tc = 0; tc < 8; ++tc) {
    #pragma unroll
    for (int t = 0; t < 3; ++t) {
      bf16x8 v;
      #pragma unroll
      for (int j = 0; j < 8; ++j) {
        const int k = t*32 + gq*8 + j;
        v[j] = (k < 88) ? (short)f2bf(w3[(tc*16 + c16)*88 + k]) : (short)0;
      }
      bw3[tc][t] = v;
    }
  }
  float b1v[3], b2v[6], b3v[8], gav[8], bev[8];
  #pragma unroll
  for (int tc = 0; tc < 3; ++tc) b1v[tc] = b1[tc*16 + c16];
  #pragma unroll
  for (int tc = 0; tc < 6; ++tc) b2v[tc] = (tc*16 + c16 < 88) ? b2[tc*16 + c16] : 0.f;
  #pragma unroll
  for (int tc = 0; tc < 8; ++tc) {
    b3v[tc] = b3[tc*16 + c16];
    gav[tc] = g[tc*16 + c16];
    bev[tc] = bb[tc*16 + c16];
  }

  const int nt = (ecnt + 15) >> 4;
  const long wid = (long)blockIdx.x*4 + wv;
  const long wstride = (long)gridDim.x*4;
  for (long tile = wid; tile < nt; tile += wstride) {
    const long i0 = tile << 4;
    const long rA = (i0 + c16 < ecnt) ? (i0 + c16) : (ecnt - 1);
    // input A-frag: row=c16, k=gq*8+j; only k<8 (gq==0) nonzero
    bf16x8 af1 = {0,0,0,0,0,0,0,0};
    if (gq == 0) {
      const float4 v0 = *(const float4*)(eat + rA*8);
      const float4 v1 = *(const float4*)(eat + rA*8 + 4);
      af1[0] = (short)f2bf(v0.x); af1[1] = (short)f2bf(v0.y);
      af1[2] = (short)f2bf(v0.z); af1[3] = (short)f2bf(v0.w);
      af1[4] = (short)f2bf(v1.x); af1[5] = (short)f2bf(v1.y);
      af1[6] = (short)f2bf(v1.z); af1[7] = (short)f2bf(v1.w);
    }
    // ---- L1: 8 -> 48 (3 ctiles, 1 ktile) ----
    #pragma unroll
    for (int tc = 0; tc < 3; ++tc) {
      f32x4 acc = {0.f, 0.f, 0.f, 0.f};
      acc = __builtin_amdgcn_mfma_f32_16x16x32_bf16(af1, bw1[tc], acc, 0, 0, 0);
      #pragma unroll
      for (int j = 0; j < 4; ++j)
        h1buf[wv][gq*4 + j][tc*16 + c16] = f2bf(LEAKY01(acc[j] + b1v[tc]));
    }
    lds_rw_fence();
    bf16x8 a2[2];
    #pragma unroll
    for (int t = 0; t < 2; ++t)
      a2[t] = *(const bf16x8*)&h1buf[wv][c16][t*32 + gq*8];
    // ---- L2: 48 -> 88 (6 ctiles, 2 ktiles) ----
    lds_rw_fence();            // a2 reads must land before h2 writes reorder
    #pragma unroll
    for (int tc = 0; tc < 6; ++tc) {
      f32x4 acc = {0.f, 0.f, 0.f, 0.f};
      #pragma unroll
      for (int t = 0; t < 2; ++t)
        acc = __builtin_amdgcn_mfma_f32_16x16x32_bf16(a2[t], bw2[tc][t], acc, 0, 0, 0);
      const int col = tc*16 + c16;
      if (col < 88) {
        #pragma unroll
        for (int j = 0; j < 4; ++j)
          h2buf[wv][gq*4 + j][col] = f2bf(LEAKY01(acc[j] + b2v[tc]));
      }
    }
    lds_rw_fence();
    bf16x8 a3[3];
    #pragma unroll
    for (int t = 0; t < 3; ++t)
      a3[t] = *(const bf16x8*)&h2buf[wv][c16][t*32 + gq*8];
    lds_rw_fence();
    // ---- L3: 88 -> 128 (8 ctiles, 3 ktiles) + bias ----
    f32x4 oa[8];
    #pragma unroll
    for (int tc = 0; tc < 8; ++tc) {
      f32x4 acc = {0.f, 0.f, 0.f, 0.f};
      #pragma unroll
      for (int t = 0; t < 3; ++t)
        acc = __builtin_amdgcn_mfma_f32_16x16x32_bf16(a3[t], bw3[tc][t], acc, 0, 0, 0);
      #pragma unroll
      for (int j = 0; j < 4; ++j) acc[j] += b3v[tc];
      oa[tc] = acc;
    }
    // ---- LN across 128 cols (16-lane group reduce per row) ----
    float vsum[4] = {0.f,0.f,0.f,0.f}, vsq[4] = {0.f,0.f,0.f,0.f};
    #pragma unroll
    for (int tc = 0; tc < 8; ++tc)
      #pragma unroll
      for (int j = 0; j < 4; ++j) { const float v = oa[tc][j]; vsum[j] += v; vsq[j] += v*v; }
    #pragma unroll
    for (int off = 1; off <= 8; off <<= 1) {
      #pragma unroll
      for (int j = 0; j < 4; ++j) {
        vsum[j] += __shfl_xor(vsum[j], off, 64);
        vsq[j]  += __shfl_xor(vsq[j], off, 64);
      }
    }
    float muv[4], rsv[4];
    #pragma unroll
    for (int j = 0; j < 4; ++j) {
      muv[j] = vsum[j] * (1.f/128.f);
      const float var = vsq[j] * (1.f/128.f) - muv[j]*muv[j];
      rsv[j] = rsqrtf(var + 1e-5f);
    }
    #pragma unroll
    for (int tc = 0; tc < 8; ++tc)
      #pragma unroll
      for (int j = 0; j < 4; ++j)
        obuf[wv][gq*4 + j][tc*16 + c16] = f2bf((oa[tc][j] - muv[j]) * rsv[j] * gav[tc] + bev[tc]);
    lds_rw_fence();
    #pragma unroll 4
    for (int r = 0; r < 16; ++r) {
      const long grow = i0 + r;
      if (grow < ecnt) {
        const u32 vv = *(const u32*)&obuf[wv][r][2*lane];
        ((u32*)ea)[grow*64 + lane] = vv;
      }
    }
    loop_mem_fence();
  }
}

// --------- MFMA linear 128x128: out(bf16) = in(fp32) @ w.T + b ------------
__global__ __launch_bounds__(256, 2) void linear128_mfma(
    const float* __restrict__ in, const float* __restrict__ w,
    const float* __restrict__ b, u16* __restrict__ out, int n)
{
  __shared__ u16 sh_t[4][16][136];   // per-wave transpose buffer
  const int tid = threadIdx.x;
  const int lane = tid & 63, wv = tid >> 6;
  const int c16 = lane & 15, g = lane >> 4;
  bf16x8 bw[8][4];
  #pragma unroll
  for (int tc = 0; tc < 8; ++tc) {
    #pragma unroll
    for (int t = 0; t < 4; ++t) {
      const float* wp = w + (tc*16 + c16)*128 + t*32 + g*8;
      bf16x8 v;
      #pragma unroll
      for (int j = 0; j < 8; ++j) v[j] = (short)f2bf(wp[j]);
      bw[tc][t] = v;
    }
  }
  float bv[8];
  #pragma unroll
  for (int tc = 0; tc < 8; ++tc) bv[tc] = b[tc*16 + c16];

  const int nt = (n + 15) >> 4;
  const long wid = (long)blockIdx.x*4 + wv;
  const long wstride = (long)gridDim.x*4;
  for (long tile = wid; tile < nt; tile += wstride) {
    const long r0 = tile << 4;
    const long rowA = (r0 + c16 < n) ? (r0 + c16) : (n - 1);
    bf16x8 af[4];
    #pragma unroll
    for (int t = 0; t < 4; ++t) {
      const float* ip = in + rowA*128 + t*32 + g*8;
      const float4 v0 = *(const float4*)ip;
      const float4 v1 = *(const float4*)(ip + 4);
      bf16x8 a;
      a[0] = (short)f2bf(v0.x); a[1] = (short)f2bf(v0.y);
      a[2] = (short)f2bf(v0.z); a[3] = (short)f2bf(v0.w);
      a[4] = (short)f2bf(v1.x); a[5] = (short)f2bf(v1.y);
      a[6] = (short)f2bf(v1.z); a[7] = (short)f2bf(v1.w);
      af[t] = a;
    }
    #pragma unroll
    for (int tc = 0; tc < 8; ++tc) {
      f32x4 acc = {0.f, 0.f, 0.f, 0.f};
      #pragma unroll
      for (int t = 0; t < 4; ++t)
        acc = __builtin_amdgcn_mfma_f32_16x16x32_bf16(af[t], bw[tc][t], acc, 0, 0, 0);
      #pragma unroll
      for (int j = 0; j < 4; ++j)
        sh_t[wv][g*4 + j][tc*16 + c16] = f2bf(acc[j] + bv[tc]);
    }
    lds_rw_fence();            // LDS writes above must land before xlane reads
    #pragma unroll 4
    for (int r = 0; r < 16; ++r) {
      const long grow = r0 + r;
      if (grow < n) {
        const u32 vv = *(const u32*)&sh_t[wv][r][2*lane];
        ((u32*)out)[grow*64 + lane] = vv;
      }
    }
    loop_mem_fence();          // next iter's writes must not hoist above reads
  }
}

// ------ MFMA fused logit: s = leaky(ea@we.T + xl[src]+xr[dst], .2) . att ---
__global__ __launch_bounds__(256, 2) void gat_logit_mfma(
    const u16* __restrict__ ea,         // chunk base (local rows)
    const u16* __restrict__ xl, const u16* __restrict__ xr,
    const int* __restrict__ src, const int* __restrict__ dst,
    const float* __restrict__ we, const float* __restrict__ att,
    float* __restrict__ s_out, int eoff, int ecnt, int E)
{
  __shared__ float sh_g[4][16][132];   // per-wave xl[src]+xr[dst] (f32)
  const int tid = threadIdx.x;
  const int lane = tid & 63, wv = tid >> 6;
  const int c16 = lane & 15, g = lane >> 4;
  bf16x8 bw[8][4];
  #pragma unroll
  for (int tc = 0; tc < 8; ++tc) {
    #pragma unroll
    for (int t = 0; t < 4; ++t) {
      const float* wp = we + (tc*16 + c16)*128 + t*32 + g*8;
      bf16x8 v;
      #pragma unroll
      for (int j = 0; j < 8; ++j) v[j] = (short)f2bf(wp[j]);
      bw[tc][t] = v;
    }
  }
  float attv[8];
  #pragma unroll
  for (int tc = 0; tc < 8; ++tc) attv[tc] = att[tc*16 + c16];

  const u32* xl32 = (const u32*)xl;
  const u32* xr32 = (const u32*)xr;
  const int nt = (ecnt + 15) >> 4;
  const long wid = (long)blockIdx.x*4 + wv;
  const long wstride = (long)gridDim.x*4;
  for (long tile = wid; tile < nt; tile += wstride) {
    const long i0 = tile << 4;          // local row base
    const long e0 = eoff + i0;          // global edge base
    int sv = 0, dv = 0;
    if (lane < 16) {
      const long eg = (e0 + lane < E) ? (e0 + lane) : (E - 1);
      sv = src[eg]; dv = dst[eg];
    }
    #pragma unroll 4
    for (int e = 0; e < 16; ++e) {
      const int srow = __shfl(sv, e, 64);
      const int drow = __shfl(dv, e, 64);
      const u32 xa = xl32[(long)srow*64 + lane];
      const u32 xb = xr32[(long)drow*64 + lane];
      float2 sg;
      sg.x = bflo(xa) + bflo(xb);
      sg.y = bfhi(xa) + bfhi(xb);
      *(float2*)&sh_g[wv][e][lane*2] = sg;
    }
    lds_rw_fence();            // gather writes must land before xlane reads
    const long rA = (i0 + c16 < ecnt) ? (i0 + c16) : (ecnt - 1);
    bf16x8 af[4];
    #pragma unroll
    for (int t = 0; t < 4; ++t)
      af[t] = *(const bf16x8*)(ea + rA*128 + t*32 + g*8);
    float p0 = 0.f, p1 = 0.f, p2 = 0.f, p3 = 0.f;
    #pragma unroll
    for (int tc = 0; tc < 8; ++tc) {
      f32x4 acc = {0.f, 0.f, 0.f, 0.f};
      #pragma unroll
      for (int t = 0; t < 4; ++t)
        acc = __builtin_amdgcn_mfma_f32_16x16x32_bf16(af[t], bw[tc][t], acc, 0, 0, 0);
      const float av = attv[tc];
      #pragma unroll
      for (int j = 0; j < 4; ++j) {
        float ev = acc[j] + sh_g[wv][g*4 + j][tc*16 + c16];
        ev = LEAKY20(ev);
        const float term = ev * av;
        if (j == 0) p0 += term; else if (j == 1) p1 += term;
        else if (j == 2) p2 += term; else p3 += term;
      }
    }
    #pragma unroll
    for (int off = 1; off <= 8; off <<= 1) {
      p0 += __shfl_xor(p0, off, 64);
      p1 += __shfl_xor(p1, off, 64);
      p2 += __shfl_xor(p2, off, 64);
      p3 += __shfl_xor(p3, off, 64);
    }
    if (c16 == 0) {
      const long rbase = e0 + g*4;
      if (rbase + 0 < E && i0 + g*4 + 0 < ecnt) s_out[rbase + 0] = p0;
      if (rbase + 1 < E && i0 + g*4 + 1 < ecnt) s_out[rbase + 1] = p1;
      if (rbase + 2 < E && i0 + g*4 + 2 < ecnt) s_out[rbase + 2] = p2;
      if (rbase + 3 < E && i0 + g*4 + 3 < ecnt) s_out[rbase + 3] = p3;
    }
    loop_mem_fence();          // next iter's writes must not hoist above reads
  }
}

// ---------------- CSR build ----------------
__global__ __launch_bounds__(256) void csr_count_kernel(
    const int* __restrict__ dst, int* __restrict__ cnt, int E)
{
  for (long e = (long)blockIdx.x*blockDim.x + threadIdx.x; e < E;
       e += (long)gridDim.x*blockDim.x)
    atomicAdd(&cnt[dst[e]], 1);
}

__global__ __launch_bounds__(1024) void csr_scan_kernel(
    const int* __restrict__ cnt, int* __restrict__ rowptr, int n)
{
  __shared__ int part[1024];
  const int t = threadIdx.x;
  const int chunk = (n + 1023) >> 10;
  const int b = t * chunk;
  const int e = min(b + chunk, n);
  int s = 0;
  for (int i = b; i < e; ++i) s += cnt[i];
  part[t] = s;
  __syncthreads();
  for (int d = 1; d < 1024; d <<= 1) {
    int v = (t >= d) ? part[t - d] : 0;
    __syncthreads();
    if (t >= d) part[t] += v;
    __syncthreads();
  }
  int pre = (t == 0) ? 0 : part[t - 1];
  for (int i = b; i < e; ++i) { rowptr[i] = pre; pre += cnt[i]; }
  if (t == 1023) rowptr[n] = pre;
}

__global__ __launch_bounds__(256) void csr_fill_kernel(
    const int* __restrict__ dst, const int* __restrict__ rowptr,
    int* __restrict__ cursor, int* __restrict__ eid, int E)
{
  for (long e = (long)blockIdx.x*blockDim.x + threadIdx.x; e < E;
       e += (long)gridDim.x*blockDim.x) {
    const int d = dst[e];
    const int pos = atomicAdd(&cursor[d], 1);
    eid[rowptr[d] + pos] = (int)e;
  }
}

// ---- per-node: softmax over CSR edges + weighted gather + LN residual ----
__global__ __launch_bounds__(256) void gat_agg_kernel(
    const float* __restrict__ s, const int* __restrict__ src,
    const int* __restrict__ rowptr, const int* __restrict__ eid,
    const u16* __restrict__ xl, const float* __restrict__ bias,
    const float* __restrict__ g, const float* __restrict__ bb,
    float* __restrict__ y, int n)
{
  const int tid = threadIdx.x;
  const int lane = tid & 63, wv = tid >> 6;
  const int wpb = blockDim.x >> 6;
  const float bi0 = bias[lane], bi1 = bias[lane + 64];
  const float g0 = g[lane], g1 = g[lane + 64];
  const float bb0 = bb[lane], bb1 = bb[lane + 64];
  for (long node = (long)blockIdx.x*wpb + wv; node < n; node += (long)gridDim.x*wpb) {
    const int beg = rowptr[node], end = rowptr[node + 1];
    float m = -INFINITY;
    for (int j = beg; j < end; ++j) m = fmaxf(m, s[eid[j]]);
    float den = 0.f, a0 = 0.f, a1 = 0.f;
    for (int j = beg; j < end; ++j) {
      const int e = eid[j];
      const float z = __expf(s[e] - m);
      den += z;
      const int sN = src[e];
      a0 += z * bf2f(xl[(long)sN*128 + lane]);
      a1 += z * bf2f(xl[(long)sN*128 + lane + 64]);
    }
    const float inv = 1.f / fmaxf(den, 1e-16f);
    const float v0 = a0*inv + bi0;
    const float v1 = a1*inv + bi1;
    float sum = v0 + v1, sq = v0*v0 + v1*v1;
    for (int off = 32; off; off >>= 1) { sum += __shfl_xor(sum, off, 64); sq += __shfl_xor(sq, off, 64); }
    const float mu = sum * (1.f/128.f);
    const float var = sq * (1.f/128.f) - mu*mu;
    const float rs = rsqrtf(var + 1e-5f);
    y[node*128 + lane]      += (v0 - mu) * rs * g0 + bb0;
    y[node*128 + lane + 64] += (v1 - mu) * rs * g1 + bb1;
  }
}

// ---------------- decoder: 128 -> 86 -> 44 -> 2, wave-per-row ----------------
__global__ __launch_bounds__(256) void decoder_kernel(
    const float* __restrict__ y,
    const float* __restrict__ w1, const float* __restrict__ b1,
    const float* __restrict__ w2, const float* __restrict__ b2,
    const float* __restrict__ w3, const float* __restrict__ b3,
    float* __restrict__ out, int n)
{
  __shared__ u32   sw1p[128*64];
  __shared__ float sw2t[86*64];
  const int tid = threadIdx.x;
  for (int i = tid; i < 128*64; i += 256) {
    int k = i >> 6, l = i & 63;
    sw1p[i] = packbf(w1[l*128 + k], w1[(64 + (l % 22))*128 + k]);
  }
  for (int i = tid; i < 86*64; i += 256) {
    int k = i >> 6, l = i & 63;
    sw2t[i] = w2[(l % 44)*86 + k];
  }
  __syncthreads();
  const int lane = tid & 63, wv = tid >> 6;
  const float b1a = b1[lane], b1b = b1[64 + (lane % 22)];
  const float b2v = b2[lane % 44];
  const float w3a = (lane < 44) ? w3[lane] : 0.f;
  const float w3b = (lane < 44) ? w3[44 + lane] : 0.f;
  const float b3a = b3[0], b3b = b3[1];
  for (long row = (long)blockIdx.x*4 + wv; row < n; row += (long)gridDim.x*4) {
    const float ya = y[row*128 + lane];
    const float yb = y[row*128 + lane + 64];
    float a0 = b1a, a1 = b1b;
    #pragma unroll
    for (int k = 0; k < 64; ++k) {
      const u32 wp = sw1p[k*64 + lane];
      const float hv = __shfl(ya, k, 64);
      a0 += hv * bflo(wp); a1 += hv * bfhi(wp);
    }
    #pragma unroll
    for (int k = 0; k < 64; ++k) {
      const u32 wp = sw1p[(64 + k)*64 + lane];
      const float hv = __shfl(yb, k, 64);
      a0 += hv * bflo(wp); a1 += hv * bfhi(wp);
    }
    const float h1a = LEAKY01(a0), h1b = LEAKY01(a1);
    float a2 = b2v;
    #pragma unroll
    for (int k = 0; k < 64; ++k) {
      const float hv = __shfl(h1a, k, 64);
      a2 += hv * sw2t[k*64 + lane];
    }
    #pragma unroll
    for (int k = 0; k < 22; ++k) {
      const float hv = __shfl(h1b, k, 64);
      a2 += hv * sw2t[(64 + k)*64 + lane];
    }
    const float h2 = LEAKY01(a2);
    float t0 = (lane < 44) ? h2 * w3a : 0.f;
    float t1 = (lane < 44) ? h2 * w3b : 0.f;
    for (int off = 32; off; off >>= 1) { t0 += __shfl_xor(t0, off, 64); t1 += __shfl_xor(t1, off, 64); }
    if (lane == 0) {
      out[row*2]     = t0 + b3a;
      out[row*2 + 1] = t1 + b3b;
    }
  }
}

__global__ __launch_bounds__(256) void zero_out_kernel(float* __restrict__ out, long n)
{
  for (long i = (long)blockIdx.x*blockDim.x + threadIdx.x; i < n;
       i += (long)gridDim.x*blockDim.x) out[i] = 0.f;
}

// ---------------------------------------------------------------------------
extern "C" void kernel_launch(void* const* d_in, const int* in_sizes, int n_in,
                              void* d_out, int out_size, void* d_ws, size_t ws_size,
                              hipStream_t stream) {
  const float* x        = (const float*)d_in[0];
  const int*   eidx     = (const int*)  d_in[1];
  const float* edge_attr= (const float*)d_in[2];
  const float* enc_w1 = (const float*)d_in[3];  const float* enc_b1 = (const float*)d_in[4];
  const float* enc_w2 = (const float*)d_in[5];  const float* enc_b2 = (const float*)d_in[6];
  const float* enc_w3 = (const float*)d_in[7];  const float* enc_b3 = (const float*)d_in[8];
  const float* enc_lg = (const float*)d_in[9];  const float* enc_lb = (const float*)d_in[10];
  const float* ee_w1  = (const float*)d_in[11]; const float* ee_b1  = (const float*)d_in[12];
  const float* ee_w2  = (const float*)d_in[13]; const float* ee_b2  = (const float*)d_in[14];
  const float* ee_w3  = (const float*)d_in[15]; const float* ee_b3  = (const float*)d_in[16];
  const float* ee_lg  = (const float*)d_in[17]; const float* ee_lb  = (const float*)d_in[18];
  const float* gat_wl = (const float*)d_in[19]; const float* gat_bl = (const float*)d_in[20];
  const float* gat_wr = (const float*)d_in[21]; const float* gat_br = (const float*)d_in[22];
  const float* gat_we = (const float*)d_in[23]; const float* gat_att= (const float*)d_in[24];
  const float* gat_bias=(const float*)d_in[25];
  const float* ln_g   = (const float*)d_in[26]; const float* ln_b   = (const float*)d_in[27];
  const float* dec_w1 = (const float*)d_in[28]; const float* dec_b1 = (const float*)d_in[29];
  const float* dec_w2 = (const float*)d_in[30]; const float* dec_b2 = (const float*)d_in[31];
  const float* dec_w3 = (const float*)d_in[32]; const float* dec_b3 = (const float*)d_in[33];
  float* out = (float*)d_out;

  const int N = in_sizes[0] / 32;
  const int E = in_sizes[2] / 8;
  const int L = in_sizes[19] / (128*128);
  const int* src = eidx;
  const int* dst = eidx + E;
  (void)n_in; (void)out_size;

  size_t off = 0;
  auto carve = [&](size_t bytes) -> char* {
    char* r = (char*)d_ws + off;
    off += (bytes + 255) & ~(size_t)255;
    return r;
  };
  float* y      = (float*)carve((size_t)N * 128 * 4);
  u16*   xl     = (u16*)  carve((size_t)N * 128 * 2);
  u16*   xr     = (u16*)  carve((size_t)N * 128 * 2);
  float* sbuf   = (float*)carve((size_t)E * 4);
  int*   rowptr = (int*)  carve((size_t)(N + 1) * 4);
  int*   eidbuf = (int*)  carve((size_t)E * 4);
  int*   cnt    = (int*)  carve((size_t)N * 4);
  int*   cursor = (int*)  carve((size_t)N * 4);
  const size_t fixedBytes = off;

  if (ws_size < fixedBytes + (size_t)4096 * 256) {
    hipLaunchKernelGGL(zero_out_kernel, dim3(256), dim3(256), 0, stream, out, (long)N*2);
    return;
  }
  const size_t eaCapEdges = (ws_size - fixedBytes) / 256;
  u16* eaBuf = (u16*)((char*)d_ws + fixedBytes);
  const bool full = eaCapEdges >= (size_t)E;
  const int Ec = full ? E : (int)(eaCapEdges & ~(size_t)1023);

  hipLaunchKernelGGL(node_enc_kernel, dim3(1024), dim3(256), 0, stream,
                     x, enc_w1, enc_b1, enc_w2, enc_b2, enc_w3, enc_b3,
                     enc_lg, enc_lb, y, N);
  hipMemsetAsync(cnt, 0, (size_t)N * 4, stream);
  hipMemsetAsync(cursor, 0, (size_t)N * 4, stream);
  hipLaunchKernelGGL(csr_count_kernel, dim3(1024), dim3(256), 0, stream, dst, cnt, E);
  hipLaunchKernelGGL(csr_scan_kernel, dim3(1), dim3(1024), 0, stream, cnt, rowptr, N);
  hipLaunchKernelGGL(csr_fill_kernel, dim3(1024), dim3(256), 0, stream, dst, rowptr, cursor, eidbuf, E);

  if (full) {
    hipLaunchKernelGGL(edge_enc_mfma, dim3(1024), dim3(256), 0, stream,
                       edge_attr, ee_w1, ee_b1, ee_w2, ee_b2, ee_w3, ee_b3,
                       ee_lg, ee_lb, eaBuf, E);
  }

  const int linGrid = ((N + 15) / 16 + 3) / 4;   // one 16-row tile per wave
  for (int l = 0; l < L; ++l) {
    const float* wl = gat_wl + (size_t)l*128*128;
    const float* bl = gat_bl + (size_t)l*128;
    const float* wr = gat_wr + (size_t)l*128*128;
    const float* br = gat_br + (size_t)l*128;
    const float* we = gat_we + (size_t)l*128*128;
    const float* at = gat_att + (size_t)l*128;
    const float* bi = gat_bias + (size_t)l*128;
    const float* lg = ln_g + (size_t)l*128;
    const float* lb = ln_b + (size_t)l*128;

    hipLaunchKernelGGL(linear128_mfma, dim3(linGrid), dim3(256), 0, stream, y, wl, bl, xl, N);
    hipLaunchKernelGGL(linear128_mfma, dim3(linGrid), dim3(256), 0, stream, y, wr, br, xr, N);

    if (full) {
      hipLaunchKernelGGL(gat_logit_mfma, dim3(1024), dim3(256), 0, stream,
                         eaBuf, xl, xr, src, dst, we, at, sbuf, 0, E, E);
    } else {
      for (int eoff = 0; eoff < E; eoff += Ec) {
        const int c = (E - eoff < Ec) ? (E - eoff) : Ec;
        hipLaunchKernelGGL(edge_enc_mfma, dim3(1024), dim3(256), 0, stream,
                           edge_attr + (size_t)eoff*8, ee_w1, ee_b1, ee_w2, ee_b2,
                           ee_w3, ee_b3, ee_lg, ee_lb, eaBuf, c);
        hipLaunchKernelGGL(gat_logit_mfma, dim3(1024), dim3(256), 0, stream,
                           eaBuf, xl, xr, src, dst, we, at, sbuf, eoff, c, E);
      }
    }

    hipLaunchKernelGGL(gat_agg_kernel, dim3(1024), dim3(256), 0, stream,
                       sbuf, src, rowptr, eidbuf, xl, bi, lg, lb, y, N);
  }

  hipLaunchKernelGGL(decoder_kernel, dim3(512), dim3(256), 0, stream,
                     y, dec_w1, dec_b1, dec_w2, dec_b2, dec_w3, dec_b3, out, N);
}

// Round 7
// 2469.078 us; speedup vs baseline: 3.4470x; 1.2318x over previous
//
#include <hip/hip_runtime.h>

// ---------------------------------------------------------------------------
// GN_NN_32873679684148: encoder MLP+LN -> 4x GATv2+LN residual -> decoder MLP
// Round 7: (1) MFMA decoder (128->86->44->2) using the proven edge_enc_mfma
// tile pattern; (2) CSR-ordered s + src_csr so gat_agg streams coalesced
// instead of chasing eid->s/src. Everything else = round 6 (passed, 3.04ms).
// N=50000, E=800000, H=128, L=4.
// ---------------------------------------------------------------------------

typedef unsigned short u16;
typedef unsigned int   u32;
typedef __attribute__((ext_vector_type(8))) short bf16x8;
typedef __attribute__((ext_vector_type(4))) float f32x4;

#define LEAKY01(a) ((a) > 0.f ? (a) : 0.01f*(a))
#define LEAKY20(a) ((a) > 0.f ? (a) : 0.2f*(a))

__device__ __forceinline__ float bf2f(u16 h) { return __uint_as_float(((u32)h) << 16); }
__device__ __forceinline__ u16 f2bf(float f) {
  u32 u = __float_as_uint(f);
  u32 r = u + 0x7fffu + ((u >> 16) & 1u);   // round-to-nearest-even
  return (u16)(r >> 16);
}
__device__ __forceinline__ float bflo(u32 p) { return __uint_as_float(p << 16); }
__device__ __forceinline__ float bfhi(u32 p) { return __uint_as_float(p & 0xffff0000u); }
__device__ __forceinline__ u32 packbf(float a, float b) {
  return (u32)f2bf(a) | ((u32)f2bf(b) << 16);
}

// fence between per-wave LDS write phase and read phase (intra-wave xlane)
__device__ __forceinline__ void lds_rw_fence() {
  __builtin_amdgcn_sched_barrier(0);
  asm volatile("s_waitcnt lgkmcnt(0)" ::: "memory");
  __builtin_amdgcn_sched_barrier(0);
}
// end-of-iteration fence: next iter's LDS writes must not hoist above reads
__device__ __forceinline__ void loop_mem_fence() {
  __builtin_amdgcn_sched_barrier(0);
  asm volatile("" ::: "memory");
}

// ---------------- node encoder: 32 -> 64 -> 96 -> 128 + LN -----------------
__global__ __launch_bounds__(256) void node_enc_kernel(
    const float* __restrict__ x,
    const float* __restrict__ w1, const float* __restrict__ b1,
    const float* __restrict__ w2, const float* __restrict__ b2,
    const float* __restrict__ w3, const float* __restrict__ b3,
    const float* __restrict__ g, const float* __restrict__ bb,
    float* __restrict__ y, int n)
{
  __shared__ float sw1t[32*64];
  __shared__ u32   sw2p[64*64];
  __shared__ u32   sw3p[96*64];
  const int tid = threadIdx.x;
  for (int i = tid; i < 32*64; i += 256) { int k = i >> 6, c = i & 63; sw1t[i] = w1[c*32 + k]; }
  for (int i = tid; i < 64*64; i += 256) { int k = i >> 6, l = i & 63; sw2p[i] = packbf(w2[l*64 + k], w2[(64 + (l & 31))*64 + k]); }
  for (int i = tid; i < 96*64; i += 256) { int k = i >> 6, l = i & 63; sw3p[i] = packbf(w3[l*96 + k], w3[(l + 64)*96 + k]); }
  __syncthreads();
  const int lane = tid & 63, wv = tid >> 6;
  const float b2a = b2[lane], b2b = b2[64 + (lane & 31)];
  const float b3a = b3[lane], b3b = b3[lane + 64];
  const float ga = g[lane], gb = g[lane + 64];
  const float ba = bb[lane], bbv = bb[lane + 64];
  for (long row = (long)blockIdx.x*4 + wv; row < n; row += (long)gridDim.x*4) {
    float xin[32];
    const float4* xp = (const float4*)(x + row*32);
    #pragma unroll
    for (int q = 0; q < 8; ++q) ((float4*)xin)[q] = xp[q];
    float h1 = b1[lane];
    #pragma unroll
    for (int k = 0; k < 32; ++k) h1 += xin[k] * sw1t[k*64 + lane];
    h1 = LEAKY01(h1);
    float a0 = b2a, a1 = b2b;
    #pragma unroll
    for (int k = 0; k < 64; ++k) {
      const u32 wp = sw2p[k*64 + lane];
      const float hv = __shfl(h1, k, 64);
      a0 += hv * bflo(wp); a1 += hv * bfhi(wp);
    }
    const float h2a = LEAKY01(a0), h2b = LEAKY01(a1);
    float o0 = b3a, o1 = b3b;
    #pragma unroll
    for (int k = 0; k < 64; ++k) {
      const u32 wp = sw3p[k*64 + lane];
      const float hv = __shfl(h2a, k, 64);
      o0 += hv * bflo(wp); o1 += hv * bfhi(wp);
    }
    #pragma unroll
    for (int k = 0; k < 32; ++k) {
      const u32 wp = sw3p[(64 + k)*64 + lane];
      const float hv = __shfl(h2b, k, 64);
      o0 += hv * bflo(wp); o1 += hv * bfhi(wp);
    }
    float sum = o0 + o1, sq = o0*o0 + o1*o1;
    for (int off = 32; off; off >>= 1) { sum += __shfl_xor(sum, off, 64); sq += __shfl_xor(sq, off, 64); }
    const float mu = sum * (1.f/128.f);
    const float var = sq * (1.f/128.f) - mu*mu;
    const float rs = rsqrtf(var + 1e-5f);
    y[row*128 + lane]      = (o0 - mu) * rs * ga + ba;
    y[row*128 + lane + 64] = (o1 - mu) * rs * gb + bbv;
  }
}

// -------- MFMA edge encoder: 8 -> 48 -> 88 -> 128 + LN, bf16 out ----------
__global__ __launch_bounds__(256, 2) void edge_enc_mfma(
    const float* __restrict__ eat,
    const float* __restrict__ w1, const float* __restrict__ b1,
    const float* __restrict__ w2, const float* __restrict__ b2,
    const float* __restrict__ w3, const float* __restrict__ b3,
    const float* __restrict__ g, const float* __restrict__ bb,
    u16* __restrict__ ea, int ecnt)
{
  __shared__ __align__(16) u16 h1buf[4][16][72];
  __shared__ __align__(16) u16 h2buf[4][16][104];
  __shared__ __align__(16) u16 obuf[4][16][136];
  const int tid = threadIdx.x;
  const int lane = tid & 63, wv = tid >> 6;
  const int c16 = lane & 15, gq = lane >> 4;
  for (int i = tid; i < 4*16*72; i += 256)  ((u16*)h1buf)[i] = 0;
  for (int i = tid; i < 4*16*104; i += 256) ((u16*)h2buf)[i] = 0;
  __syncthreads();

  bf16x8 bw1[3];
  #pragma unroll
  for (int tc = 0; tc < 3; ++tc) {
    bf16x8 v;
    #pragma unroll
    for (int j = 0; j < 8; ++j) {
      const int k = gq*8 + j;
      v[j] = (k < 8) ? (short)f2bf(w1[(tc*16 + c16)*8 + k]) : (short)0;
    }
    bw1[tc] = v;
  }
  bf16x8 bw2[6][2];
  #pragma unroll
  for (int tc = 0; tc < 6; ++tc) {
    const int col = tc*16 + c16;
    #pragma unroll
    for (int t = 0; t < 2; ++t) {
      bf16x8 v;
      #pragma unroll
      for (int j = 0; j < 8; ++j) {
        const int k = t*32 + gq*8 + j;
        v[j] = (col < 88 && k < 48) ? (short)f2bf(w2[col*48 + k]) : (short)0;
      }
      bw2[tc][t] = v;
    }
  }
  bf16x8 bw3[8][3];
  #pragma unroll
  for (int tc = 0; tc < 8; ++tc) {
    #pragma unroll
    for (int t = 0; t < 3; ++t) {
      bf16x8 v;
      #pragma unroll
      for (int j = 0; j < 8; ++j) {
        const int k = t*32 + gq*8 + j;
        v[j] = (k < 88) ? (short)f2bf(w3[(tc*16 + c16)*88 + k]) : (short)0;
      }
      bw3[tc][t] = v;
    }
  }
  float b1v[3], b2v[6], b3v[8], gav[8], bev[8];
  #pragma unroll
  for (int tc = 0; tc < 3; ++tc) b1v[tc] = b1[tc*16 + c16];
  #pragma unroll
  for (int tc = 0; tc < 6; ++tc) b2v[tc] = (tc*16 + c16 < 88) ? b2[tc*16 + c16] : 0.f;
  #pragma unroll
  for (int tc = 0; tc < 8; ++tc) {
    b3v[tc] = b3[tc*16 + c16];
    gav[tc] = g[tc*16 + c16];
    bev[tc] = bb[tc*16 + c16];
  }

  const int nt = (ecnt + 15) >> 4;
  const long wid = (long)blockIdx.x*4 + wv;
  const long wstride = (long)gridDim.x*4;
  for (long tile = wid; tile < nt; tile += wstride) {
    const long i0 = tile << 4;
    const long rA = (i0 + c16 < ecnt) ? (i0 + c16) : (ecnt - 1);
    bf16x8 af1 = {0,0,0,0,0,0,0,0};
    if (gq == 0) {
      const float4 v0 = *(const float4*)(eat + rA*8);
      const float4 v1 = *(const float4*)(eat + rA*8 + 4);
      af1[0] = (short)f2bf(v0.x); af1[1] = (short)f2bf(v0.y);
      af1[2] = (short)f2bf(v0.z); af1[3] = (short)f2bf(v0.w);
      af1[4] = (short)f2bf(v1.x); af1[5] = (short)f2bf(v1.y);
      af1[6] = (short)f2bf(v1.z); af1[7] = (short)f2bf(v1.w);
    }
    #pragma unroll
    for (int tc = 0; tc < 3; ++tc) {
      f32x4 acc = {0.f, 0.f, 0.f, 0.f};
      acc = __builtin_amdgcn_mfma_f32_16x16x32_bf16(af1, bw1[tc], acc, 0, 0, 0);
      #pragma unroll
      for (int j = 0; j < 4; ++j)
        h1buf[wv][gq*4 + j][tc*16 + c16] = f2bf(LEAKY01(acc[j] + b1v[tc]));
    }
    lds_rw_fence();
    bf16x8 a2[2];
    #pragma unroll
    for (int t = 0; t < 2; ++t)
      a2[t] = *(const bf16x8*)&h1buf[wv][c16][t*32 + gq*8];
    lds_rw_fence();
    #pragma unroll
    for (int tc = 0; tc < 6; ++tc) {
      f32x4 acc = {0.f, 0.f, 0.f, 0.f};
      #pragma unroll
      for (int t = 0; t < 2; ++t)
        acc = __builtin_amdgcn_mfma_f32_16x16x32_bf16(a2[t], bw2[tc][t], acc, 0, 0, 0);
      const int col = tc*16 + c16;
      if (col < 88) {
        #pragma unroll
        for (int j = 0; j < 4; ++j)
          h2buf[wv][gq*4 + j][col] = f2bf(LEAKY01(acc[j] + b2v[tc]));
      }
    }
    lds_rw_fence();
    bf16x8 a3[3];
    #pragma unroll
    for (int t = 0; t < 3; ++t)
      a3[t] = *(const bf16x8*)&h2buf[wv][c16][t*32 + gq*8];
    lds_rw_fence();
    f32x4 oa[8];
    #pragma unroll
    for (int tc = 0; tc < 8; ++tc) {
      f32x4 acc = {0.f, 0.f, 0.f, 0.f};
      #pragma unroll
      for (int t = 0; t < 3; ++t)
        acc = __builtin_amdgcn_mfma_f32_16x16x32_bf16(a3[t], bw3[tc][t], acc, 0, 0, 0);
      #pragma unroll
      for (int j = 0; j < 4; ++j) acc[j] += b3v[tc];
      oa[tc] = acc;
    }
    float vsum[4] = {0.f,0.f,0.f,0.f}, vsq[4] = {0.f,0.f,0.f,0.f};
    #pragma unroll
    for (int tc = 0; tc < 8; ++tc)
      #pragma unroll
      for (int j = 0; j < 4; ++j) { const float v = oa[tc][j]; vsum[j] += v; vsq[j] += v*v; }
    #pragma unroll
    for (int off = 1; off <= 8; off <<= 1) {
      #pragma unroll
      for (int j = 0; j < 4; ++j) {
        vsum[j] += __shfl_xor(vsum[j], off, 64);
        vsq[j]  += __shfl_xor(vsq[j], off, 64);
      }
    }
    float muv[4], rsv[4];
    #pragma unroll
    for (int j = 0; j < 4; ++j) {
      muv[j] = vsum[j] * (1.f/128.f);
      const float var = vsq[j] * (1.f/128.f) - muv[j]*muv[j];
      rsv[j] = rsqrtf(var + 1e-5f);
    }
    #pragma unroll
    for (int tc = 0; tc < 8; ++tc)
      #pragma unroll
      for (int j = 0; j < 4; ++j)
        obuf[wv][gq*4 + j][tc*16 + c16] = f2bf((oa[tc][j] - muv[j]) * rsv[j] * gav[tc] + bev[tc]);
    lds_rw_fence();
    #pragma unroll 4
    for (int r = 0; r < 16; ++r) {
      const long grow = i0 + r;
      if (grow < ecnt) {
        const u32 vv = *(const u32*)&obuf[wv][r][2*lane];
        ((u32*)ea)[grow*64 + lane] = vv;
      }
    }
    loop_mem_fence();
  }
}

// --------- MFMA linear 128x128: out(bf16) = in(fp32) @ w.T + b ------------
__global__ __launch_bounds__(256, 2) void linear128_mfma(
    const float* __restrict__ in, const float* __restrict__ w,
    const float* __restrict__ b, u16* __restrict__ out, int n)
{
  __shared__ u16 sh_t[4][16][136];
  const int tid = threadIdx.x;
  const int lane = tid & 63, wv = tid >> 6;
  const int c16 = lane & 15, g = lane >> 4;
  bf16x8 bw[8][4];
  #pragma unroll
  for (int tc = 0; tc < 8; ++tc) {
    #pragma unroll
    for (int t = 0; t < 4; ++t) {
      const float* wp = w + (tc*16 + c16)*128 + t*32 + g*8;
      bf16x8 v;
      #pragma unroll
      for (int j = 0; j < 8; ++j) v[j] = (short)f2bf(wp[j]);
      bw[tc][t] = v;
    }
  }
  float bv[8];
  #pragma unroll
  for (int tc = 0; tc < 8; ++tc) bv[tc] = b[tc*16 + c16];

  const int nt = (n + 15) >> 4;
  const long wid = (long)blockIdx.x*4 + wv;
  const long wstride = (long)gridDim.x*4;
  for (long tile = wid; tile < nt; tile += wstride) {
    const long r0 = tile << 4;
    const long rowA = (r0 + c16 < n) ? (r0 + c16) : (n - 1);
    bf16x8 af[4];
    #pragma unroll
    for (int t = 0; t < 4; ++t) {
      const float* ip = in + rowA*128 + t*32 + g*8;
      const float4 v0 = *(const float4*)ip;
      const float4 v1 = *(const float4*)(ip + 4);
      bf16x8 a;
      a[0] = (short)f2bf(v0.x); a[1] = (short)f2bf(v0.y);
      a[2] = (short)f2bf(v0.z); a[3] = (short)f2bf(v0.w);
      a[4] = (short)f2bf(v1.x); a[5] = (short)f2bf(v1.y);
      a[6] = (short)f2bf(v1.z); a[7] = (short)f2bf(v1.w);
      af[t] = a;
    }
    #pragma unroll
    for (int tc = 0; tc < 8; ++tc) {
      f32x4 acc = {0.f, 0.f, 0.f, 0.f};
      #pragma unroll
      for (int t = 0; t < 4; ++t)
        acc = __builtin_amdgcn_mfma_f32_16x16x32_bf16(af[t], bw[tc][t], acc, 0, 0, 0);
      #pragma unroll
      for (int j = 0; j < 4; ++j)
        sh_t[wv][g*4 + j][tc*16 + c16] = f2bf(acc[j] + bv[tc]);
    }
    lds_rw_fence();
    #pragma unroll 4
    for (int r = 0; r < 16; ++r) {
      const long grow = r0 + r;
      if (grow < n) {
        const u32 vv = *(const u32*)&sh_t[wv][r][2*lane];
        ((u32*)out)[grow*64 + lane] = vv;
      }
    }
    loop_mem_fence();
  }
}

// ------ MFMA fused logit: s = leaky(ea@we.T + xl[src]+xr[dst], .2) . att ---
// writes s into CSR slot pos[e] so gat_agg streams coalesced.
__global__ __launch_bounds__(256, 2) void gat_logit_mfma(
    const u16* __restrict__ ea,
    const u16* __restrict__ xl, const u16* __restrict__ xr,
    const int* __restrict__ src, const int* __restrict__ dst,
    const int* __restrict__ posbuf,
    const float* __restrict__ we, const float* __restrict__ att,
    float* __restrict__ s_csr, int eoff, int ecnt, int E)
{
  __shared__ float sh_g[4][16][132];
  const int tid = threadIdx.x;
  const int lane = tid & 63, wv = tid >> 6;
  const int c16 = lane & 15, g = lane >> 4;
  bf16x8 bw[8][4];
  #pragma unroll
  for (int tc = 0; tc < 8; ++tc) {
    #pragma unroll
    for (int t = 0; t < 4; ++t) {
      const float* wp = we + (tc*16 + c16)*128 + t*32 + g*8;
      bf16x8 v;
      #pragma unroll
      for (int j = 0; j < 8; ++j) v[j] = (short)f2bf(wp[j]);
      bw[tc][t] = v;
    }
  }
  float attv[8];
  #pragma unroll
  for (int tc = 0; tc < 8; ++tc) attv[tc] = att[tc*16 + c16];

  const u32* xl32 = (const u32*)xl;
  const u32* xr32 = (const u32*)xr;
  const int nt = (ecnt + 15) >> 4;
  const long wid = (long)blockIdx.x*4 + wv;
  const long wstride = (long)gridDim.x*4;
  for (long tile = wid; tile < nt; tile += wstride) {
    const long i0 = tile << 4;
    const long e0 = eoff + i0;
    int sv = 0, dv = 0;
    if (lane < 16) {
      const long eg = (e0 + lane < E) ? (e0 + lane) : (E - 1);
      sv = src[eg]; dv = dst[eg];
    }
    #pragma unroll 4
    for (int e = 0; e < 16; ++e) {
      const int srow = __shfl(sv, e, 64);
      const int drow = __shfl(dv, e, 64);
      const u32 xa = xl32[(long)srow*64 + lane];
      const u32 xb = xr32[(long)drow*64 + lane];
      float2 sg;
      sg.x = bflo(xa) + bflo(xb);
      sg.y = bfhi(xa) + bfhi(xb);
      *(float2*)&sh_g[wv][e][lane*2] = sg;
    }
    lds_rw_fence();
    const long rA = (i0 + c16 < ecnt) ? (i0 + c16) : (ecnt - 1);
    bf16x8 af[4];
    #pragma unroll
    for (int t = 0; t < 4; ++t)
      af[t] = *(const bf16x8*)(ea + rA*128 + t*32 + g*8);
    float p0 = 0.f, p1 = 0.f, p2 = 0.f, p3 = 0.f;
    #pragma unroll
    for (int tc = 0; tc < 8; ++tc) {
      f32x4 acc = {0.f, 0.f, 0.f, 0.f};
      #pragma unroll
      for (int t = 0; t < 4; ++t)
        acc = __builtin_amdgcn_mfma_f32_16x16x32_bf16(af[t], bw[tc][t], acc, 0, 0, 0);
      const float av = attv[tc];
      #pragma unroll
      for (int j = 0; j < 4; ++j) {
        float ev = acc[j] + sh_g[wv][g*4 + j][tc*16 + c16];
        ev = LEAKY20(ev);
        const float term = ev * av;
        if (j == 0) p0 += term; else if (j == 1) p1 += term;
        else if (j == 2) p2 += term; else p3 += term;
      }
    }
    #pragma unroll
    for (int off = 1; off <= 8; off <<= 1) {
      p0 += __shfl_xor(p0, off, 64);
      p1 += __shfl_xor(p1, off, 64);
      p2 += __shfl_xor(p2, off, 64);
      p3 += __shfl_xor(p3, off, 64);
    }
    if (c16 == 0) {
      const long rbase = e0 + g*4;
      if (rbase + 0 < E && i0 + g*4 + 0 < ecnt) s_csr[posbuf[rbase + 0]] = p0;
      if (rbase + 1 < E && i0 + g*4 + 1 < ecnt) s_csr[posbuf[rbase + 1]] = p1;
      if (rbase + 2 < E && i0 + g*4 + 2 < ecnt) s_csr[posbuf[rbase + 2]] = p2;
      if (rbase + 3 < E && i0 + g*4 + 3 < ecnt) s_csr[posbuf[rbase + 3]] = p3;
    }
    loop_mem_fence();
  }
}

// ---------------- CSR build ----------------
__global__ __launch_bounds__(256) void csr_count_kernel(
    const int* __restrict__ dst, int* __restrict__ cnt, int E)
{
  for (long e = (long)blockIdx.x*blockDim.x + threadIdx.x; e < E;
       e += (long)gridDim.x*blockDim.x)
    atomicAdd(&cnt[dst[e]], 1);
}

__global__ __launch_bounds__(1024) void csr_scan_kernel(
    const int* __restrict__ cnt, int* __restrict__ rowptr, int n)
{
  __shared__ int part[1024];
  const int t = threadIdx.x;
  const int chunk = (n + 1023) >> 10;
  const int b = t * chunk;
  const int e = min(b + chunk, n);
  int s = 0;
  for (int i = b; i < e; ++i) s += cnt[i];
  part[t] = s;
  __syncthreads();
  for (int d = 1; d < 1024; d <<= 1) {
    int v = (t >= d) ? part[t - d] : 0;
    __syncthreads();
    if (t >= d) part[t] += v;
    __syncthreads();
  }
  int pre = (t == 0) ? 0 : part[t - 1];
  for (int i = b; i < e; ++i) { rowptr[i] = pre; pre += cnt[i]; }
  if (t == 1023) rowptr[n] = pre;
}

// fill: pos[e] = CSR slot; src_csr[slot] = src[e]
__global__ __launch_bounds__(256) void csr_fill_kernel(
    const int* __restrict__ src, const int* __restrict__ dst,
    const int* __restrict__ rowptr, int* __restrict__ cursor,
    int* __restrict__ posbuf, int* __restrict__ srccsr, int E)
{
  for (long e = (long)blockIdx.x*blockDim.x + threadIdx.x; e < E;
       e += (long)gridDim.x*blockDim.x) {
    const int d = dst[e];
    const int pos = rowptr[d] + atomicAdd(&cursor[d], 1);
    posbuf[e] = pos;
    srccsr[pos] = src[e];
  }
}

// ---- per-node: softmax over CSR edges + weighted gather + LN residual ----
__global__ __launch_bounds__(256) void gat_agg_kernel(
    const float* __restrict__ s_csr, const int* __restrict__ srccsr,
    const int* __restrict__ rowptr,
    const u16* __restrict__ xl, const float* __restrict__ bias,
    const float* __restrict__ g, const float* __restrict__ bb,
    float* __restrict__ y, int n)
{
  const int tid = threadIdx.x;
  const int lane = tid & 63, wv = tid >> 6;
  const int wpb = blockDim.x >> 6;
  const float bi0 = bias[lane], bi1 = bias[lane + 64];
  const float g0 = g[lane], g1 = g[lane + 64];
  const float bb0 = bb[lane], bb1 = bb[lane + 64];
  for (long node = (long)blockIdx.x*wpb + wv; node < n; node += (long)gridDim.x*wpb) {
    const int beg = rowptr[node], end = rowptr[node + 1];
    float m = -INFINITY;
    for (int j = beg; j < end; ++j) m = fmaxf(m, s_csr[j]);
    float den = 0.f, a0 = 0.f, a1 = 0.f;
    for (int j = beg; j < end; ++j) {
      const float z = __expf(s_csr[j] - m);
      den += z;
      const int sN = srccsr[j];
      a0 += z * bf2f(xl[(long)sN*128 + lane]);
      a1 += z * bf2f(xl[(long)sN*128 + lane + 64]);
    }
    const float inv = 1.f / fmaxf(den, 1e-16f);
    const float v0 = a0*inv + bi0;
    const float v1 = a1*inv + bi1;
    float sum = v0 + v1, sq = v0*v0 + v1*v1;
    for (int off = 32; off; off >>= 1) { sum += __shfl_xor(sum, off, 64); sq += __shfl_xor(sq, off, 64); }
    const float mu = sum * (1.f/128.f);
    const float var = sq * (1.f/128.f) - mu*mu;
    const float rs = rsqrtf(var + 1e-5f);
    y[node*128 + lane]      += (v0 - mu) * rs * g0 + bb0;
    y[node*128 + lane + 64] += (v1 - mu) * rs * g1 + bb1;
  }
}

// ------------- MFMA decoder: 128 -> 86 -> 44 -> 2, wave = 16 rows ----------
__global__ __launch_bounds__(256, 2) void decoder_mfma(
    const float* __restrict__ y,
    const float* __restrict__ w1, const float* __restrict__ b1,
    const float* __restrict__ w2, const float* __restrict__ b2,
    const float* __restrict__ w3, const float* __restrict__ b3,
    float* __restrict__ out, int n)
{
  __shared__ __align__(16) u16 h1buf[4][16][104];  // cols 0..95 used, 96..103 pad=0
  __shared__ __align__(16) u16 h2buf[4][16][48];   // cols 0..43 real, 44..47 = 0
  const int tid = threadIdx.x;
  const int lane = tid & 63, wv = tid >> 6;
  const int c16 = lane & 15, gq = lane >> 4;
  for (int i = tid; i < 4*16*104; i += 256) ((u16*)h1buf)[i] = 0;
  for (int i = tid; i < 4*16*48; i += 256)  ((u16*)h2buf)[i] = 0;
  __syncthreads();

  // B1: 6 ctiles (96 cols, pad>=86 zero) x 4 ktiles (K=128)
  bf16x8 bw1[6][4];
  #pragma unroll
  for (int tc = 0; tc < 6; ++tc) {
    const int col = tc*16 + c16;
    #pragma unroll
    for (int t = 0; t < 4; ++t) {
      bf16x8 v;
      #pragma unroll
      for (int j = 0; j < 8; ++j) {
        const int k = t*32 + gq*8 + j;
        v[j] = (col < 86) ? (short)f2bf(w1[col*128 + k]) : (short)0;
      }
      bw1[tc][t] = v;
    }
  }
  // B2: 3 ctiles (48 cols, pad>=44 zero) x 3 ktiles (K=96 covering 86)
  bf16x8 bw2[3][3];
  #pragma unroll
  for (int tc = 0; tc < 3; ++tc) {
    const int col = tc*16 + c16;
    #pragma unroll
    for (int t = 0; t < 3; ++t) {
      bf16x8 v;
      #pragma unroll
      for (int j = 0; j < 8; ++j) {
        const int k = t*32 + gq*8 + j;
        v[j] = (col < 44 && k < 86) ? (short)f2bf(w2[col*86 + k]) : (short)0;
      }
      bw2[tc][t] = v;
    }
  }
  float b1v[6], b2v[3];
  #pragma unroll
  for (int tc = 0; tc < 6; ++tc) b1v[tc] = (tc*16 + c16 < 86) ? b1[tc*16 + c16] : 0.f;
  #pragma unroll
  for (int tc = 0; tc < 3; ++tc) b2v[tc] = (tc*16 + c16 < 44) ? b2[tc*16 + c16] : 0.f;
  // L3 weights: lane group gq handles k = gq*11 .. gq*11+10 (44 = 4*11)
  float w3a[11], w3b[11];
  #pragma unroll
  for (int i = 0; i < 11; ++i) { w3a[i] = w3[gq*11 + i]; w3b[i] = w3[44 + gq*11 + i]; }
  const float b3a = b3[0], b3b = b3[1];

  const int nt = (n + 15) >> 4;
  const long wid = (long)blockIdx.x*4 + wv;
  const long wstride = (long)gridDim.x*4;
  for (long tile = wid; tile < nt; tile += wstride) {
    const long r0 = tile << 4;
    const long rowA = (r0 + c16 < n) ? (r0 + c16) : (n - 1);
    bf16x8 af[4];
    #pragma unroll
    for (int t = 0; t < 4; ++t) {
      const float* ip = y + rowA*128 + t*32 + gq*8;
      const float4 v0 = *(const float4*)ip;
      const float4 v1 = *(const float4*)(ip + 4);
      bf16x8 a;
      a[0] = (short)f2bf(v0.x); a[1] = (short)f2bf(v0.y);
      a[2] = (short)f2bf(v0.z); a[3] = (short)f2bf(v0.w);
      a[4] = (short)f2bf(v1.x); a[5] = (short)f2bf(v1.y);
      a[6] = (short)f2bf(v1.z); a[7] = (short)f2bf(v1.w);
      af[t] = a;
    }
    // L1: 128 -> 86 (pad to 96)
    #pragma unroll
    for (int tc = 0; tc < 6; ++tc) {
      f32x4 acc = {0.f, 0.f, 0.f, 0.f};
      #pragma unroll
      for (int t = 0; t < 4; ++t)
        acc = __builtin_amdgcn_mfma_f32_16x16x32_bf16(af[t], bw1[tc][t], acc, 0, 0, 0);
      #pragma unroll
      for (int j = 0; j < 4; ++j)
        h1buf[wv][gq*4 + j][tc*16 + c16] = f2bf(LEAKY01(acc[j] + b1v[tc]));
    }
    lds_rw_fence();
    bf16x8 a2[3];
    #pragma unroll
    for (int t = 0; t < 3; ++t)
      a2[t] = *(const bf16x8*)&h1buf[wv][c16][t*32 + gq*8];
    lds_rw_fence();
    // L2: 86 -> 44 (pad to 48)
    #pragma unroll
    for (int tc = 0; tc < 3; ++tc) {
      f32x4 acc = {0.f, 0.f, 0.f, 0.f};
      #pragma unroll
      for (int t = 0; t < 3; ++t)
        acc = __builtin_amdgcn_mfma_f32_16x16x32_bf16(a2[t], bw2[tc][t], acc, 0, 0, 0);
      #pragma unroll
      for (int j = 0; j < 4; ++j)
        h2buf[wv][gq*4 + j][tc*16 + c16] = f2bf(LEAKY01(acc[j] + b2v[tc]));
    }
    lds_rw_fence();
    // L3: 44 -> 2; row=c16, 4 lanes (gq) split k
    float t0 = 0.f, t1 = 0.f;
    #pragma unroll
    for (int i = 0; i < 11; ++i) {
      const float hv = bf2f(h2buf[wv][c16][gq*11 + i]);
      t0 += hv * w3a[i];
      t1 += hv * w3b[i];
    }
    t0 += __shfl_xor(t0, 16, 64); t0 += __shfl_xor(t0, 32, 64);
    t1 += __shfl_xor(t1, 16, 64); t1 += __shfl_xor(t1, 32, 64);
    if (gq == 0 && r0 + c16 < n) {
      float2 o; o.x = t0 + b3a; o.y = t1 + b3b;
      *(float2*)(out + (r0 + c16)*2) = o;
    }
    loop_mem_fence();
  }
}

__global__ __launch_bounds__(256) void zero_out_kernel(float* __restrict__ out, long n)
{
  for (long i = (long)blockIdx.x*blockDim.x + threadIdx.x; i < n;
       i += (long)gridDim.x*blockDim.x) out[i] = 0.f;
}

// ---------------------------------------------------------------------------
extern "C" void kernel_launch(void* const* d_in, const int* in_sizes, int n_in,
                              void* d_out, int out_size, void* d_ws, size_t ws_size,
                              hipStream_t stream) {
  const float* x        = (const float*)d_in[0];
  const int*   eidx     = (const int*)  d_in[1];
  const float* edge_attr= (const float*)d_in[2];
  const float* enc_w1 = (const float*)d_in[3];  const float* enc_b1 = (const float*)d_in[4];
  const float* enc_w2 = (const float*)d_in[5];  const float* enc_b2 = (const float*)d_in[6];
  const float* enc_w3 = (const float*)d_in[7];  const float* enc_b3 = (const float*)d_in[8];
  const float* enc_lg = (const float*)d_in[9];  const float* enc_lb = (const float*)d_in[10];
  const float* ee_w1  = (const float*)d_in[11]; const float* ee_b1  = (const float*)d_in[12];
  const float* ee_w2  = (const float*)d_in[13]; const float* ee_b2  = (const float*)d_in[14];
  const float* ee_w3  = (const float*)d_in[15]; const float* ee_b3  = (const float*)d_in[16];
  const float* ee_lg  = (const float*)d_in[17]; const float* ee_lb  = (const float*)d_in[18];
  const float* gat_wl = (const float*)d_in[19]; const float* gat_bl = (const float*)d_in[20];
  const float* gat_wr = (const float*)d_in[21]; const float* gat_br = (const float*)d_in[22];
  const float* gat_we = (const float*)d_in[23]; const float* gat_att= (const float*)d_in[24];
  const float* gat_bias=(const float*)d_in[25];
  const float* ln_g   = (const float*)d_in[26]; const float* ln_b   = (const float*)d_in[27];
  const float* dec_w1 = (const float*)d_in[28]; const float* dec_b1 = (const float*)d_in[29];
  const float* dec_w2 = (const float*)d_in[30]; const float* dec_b2 = (const float*)d_in[31];
  const float* dec_w3 = (const float*)d_in[32]; const float* dec_b3 = (const float*)d_in[33];
  float* out = (float*)d_out;

  const int N = in_sizes[0] / 32;
  const int E = in_sizes[2] / 8;
  const int L = in_sizes[19] / (128*128);
  const int* src = eidx;
  const int* dst = eidx + E;
  (void)n_in; (void)out_size;

  size_t off = 0;
  auto carve = [&](size_t bytes) -> char* {
    char* r = (char*)d_ws + off;
    off += (bytes + 255) & ~(size_t)255;
    return r;
  };
  float* y      = (float*)carve((size_t)N * 128 * 4);
  u16*   xl     = (u16*)  carve((size_t)N * 128 * 2);
  u16*   xr     = (u16*)  carve((size_t)N * 128 * 2);
  float* sbuf   = (float*)carve((size_t)E * 4);        // s in CSR order
  int*   rowptr = (int*)  carve((size_t)(N + 1) * 4);
  int*   posbuf = (int*)  carve((size_t)E * 4);        // edge -> CSR slot
  int*   srccsr = (int*)  carve((size_t)E * 4);        // src in CSR order
  int*   cnt    = (int*)  carve((size_t)N * 4);
  int*   cursor = (int*)  carve((size_t)N * 4);
  const size_t fixedBytes = off;

  if (ws_size < fixedBytes + (size_t)4096 * 256) {
    hipLaunchKernelGGL(zero_out_kernel, dim3(256), dim3(256), 0, stream, out, (long)N*2);
    return;
  }
  const size_t eaCapEdges = (ws_size - fixedBytes) / 256;
  u16* eaBuf = (u16*)((char*)d_ws + fixedBytes);
  const bool full = eaCapEdges >= (size_t)E;
  const int Ec = full ? E : (int)(eaCapEdges & ~(size_t)1023);

  hipLaunchKernelGGL(node_enc_kernel, dim3(1024), dim3(256), 0, stream,
                     x, enc_w1, enc_b1, enc_w2, enc_b2, enc_w3, enc_b3,
                     enc_lg, enc_lb, y, N);
  hipMemsetAsync(cnt, 0, (size_t)N * 4, stream);
  hipMemsetAsync(cursor, 0, (size_t)N * 4, stream);
  hipLaunchKernelGGL(csr_count_kernel, dim3(1024), dim3(256), 0, stream, dst, cnt, E);
  hipLaunchKernelGGL(csr_scan_kernel, dim3(1), dim3(1024), 0, stream, cnt, rowptr, N);
  hipLaunchKernelGGL(csr_fill_kernel, dim3(1024), dim3(256), 0, stream,
                     src, dst, rowptr, cursor, posbuf, srccsr, E);

  if (full) {
    hipLaunchKernelGGL(edge_enc_mfma, dim3(1024), dim3(256), 0, stream,
                       edge_attr, ee_w1, ee_b1, ee_w2, ee_b2, ee_w3, ee_b3,
                       ee_lg, ee_lb, eaBuf, E);
  }

  const int linGrid = ((N + 15) / 16 + 3) / 4;   // one 16-row tile per wave
  for (int l = 0; l < L; ++l) {
    const float* wl = gat_wl + (size_t)l*128*128;
    const float* bl = gat_bl + (size_t)l*128;
    const float* wr = gat_wr + (size_t)l*128*128;
    const float* br = gat_br + (size_t)l*128;
    const float* we = gat_we + (size_t)l*128*128;
    const float* at = gat_att + (size_t)l*128;
    const float* bi = gat_bias + (size_t)l*128;
    const float* lg = ln_g + (size_t)l*128;
    const float* lb = ln_b + (size_t)l*128;

    hipLaunchKernelGGL(linear128_mfma, dim3(linGrid), dim3(256), 0, stream, y, wl, bl, xl, N);
    hipLaunchKernelGGL(linear128_mfma, dim3(linGrid), dim3(256), 0, stream, y, wr, br, xr, N);

    if (full) {
      hipLaunchKernelGGL(gat_logit_mfma, dim3(1024), dim3(256), 0, stream,
                         eaBuf, xl, xr, src, dst, posbuf, we, at, sbuf, 0, E, E);
    } else {
      for (int eoff = 0; eoff < E; eoff += Ec) {
        const int c = (E - eoff < Ec) ? (E - eoff) : Ec;
        hipLaunchKernelGGL(edge_enc_mfma, dim3(1024), dim3(256), 0, stream,
                           edge_attr + (size_t)eoff*8, ee_w1, ee_b1, ee_w2, ee_b2,
                           ee_w3, ee_b3, ee_lg, ee_lb, eaBuf, c);
        hipLaunchKernelGGL(gat_logit_mfma, dim3(1024), dim3(256), 0, stream,
                           eaBuf, xl, xr, src, dst, posbuf, we, at, sbuf, eoff, c, E);
      }
    }

    hipLaunchKernelGGL(gat_agg_kernel, dim3(1024), dim3(256), 0, stream,
                       sbuf, srccsr, rowptr, xl, bi, lg, lb, y, N);
  }

  hipLaunchKernelGGL(decoder_mfma, dim3(linGrid), dim3(256), 0, stream,
                     y, dec_w1, dec_b1, dec_w2, dec_b2, dec_w3, dec_b3, out, N);
}